// Round 14
// baseline (657.718 us; speedup 1.0000x reference)
//
#include <hip/hip_runtime.h>
#include <math.h>

#define VOCAB 8000
#define NN 2048   /* B*T */

typedef unsigned short u16;
typedef __attribute__((ext_vector_type(8))) short short8v;
typedef __attribute__((ext_vector_type(4))) short short4v;
typedef __attribute__((ext_vector_type(4))) float float4v;
typedef __attribute__((ext_vector_type(4))) int int4v;

// ---- workspace offsets (in float slots) ----
#define OFF_WPBF   0ul          /* bf16 [2][8000][256]      2,048,000 */
#define OFF_WDEC   2048000ul    /* bf16 [2][1024][512]        524,288 */
#define OFF_XENC   2572288ul    /* bf16 [2][128][16][256]     524,288 */
#define OFF_H0BF   4153344ul    /* bf16 [2][2048][256]        524,288 */
#define OFF_DECX   4677632ul    /* bf16 [2][3][2048][256]   1,572,864 */
#define OFF_CDEC   6250496ul    /* f32  [2][2048][256]      1,048,576 */
#define OFF_HSBF   7299072ul    /* bf16 [8][2048][256]      2,097,152 */
#define OFF_GBUF   9396224ul    /* f32  4,194,304 (aliased: xpT, then decoder gBuf, then partials[16384][16]) */
#define OFF_LOGZ   13590528ul   /* f32  [8][2048]              16,384 */
#define OFF_GCH    13606912ul   /* f32  [2][3][2048]           12,288 */
#define OFF_GTG    13619200ul   /* f32  [2][3][2048]           12,288 */
#define OFF_P      13631488ul   /* f32  [128][3][16]            6,144 */
#define OFF_WTOK   13637632ul   /* int  [2][3][2048]           12,288 */
#define OFF_XP0    13649920ul   /* f32  [2][1024]               2,048 */
#define OFF_ENCW   13652032ul   /* bf16 [1024][512]           262,144 */
#define OFF_SENC   13914240ul   /* f32  [1024] dequant scale    1,024 */
#define OFF_SQ     13915264ul   /* f32  [1024] quant scale      1,024 */
#define OFF_WQI8   13916288ul   /* i8   [16384][16]            65,536 f32 slots */

__device__ __forceinline__ float sigf(float x) { return 1.0f / (1.0f + __expf(-x)); }
__device__ __forceinline__ float tanhsafe(float x) {
    x = fminf(15.0f, fmaxf(-15.0f, x));
    float e = __expf(2.0f * x);
    return (e - 1.0f) / (e + 1.0f);
}
__device__ __forceinline__ u16 f2bf(float f) {
    union { float f; unsigned int u; } x; x.f = f;
    return (u16)((x.u + 0x7fffu + ((x.u >> 16) & 1u)) >> 16);
}
__device__ __forceinline__ float bf2f(u16 x) {
    union { unsigned int u; float f; } v; v.u = ((unsigned int)x) << 16;
    return v.f;
}

// MFMA fragment load from a swizzled LDS tile (bf16). Rows of SB bytes; lane l reads
// row (row + (l&15)), 8 contiguous bf16 at k + (l>>4)*8. XOR swizzle (r&7)<<4.
__device__ __forceinline__ short8v ldfrag(const u16* lds, int row, int k, int lane, int SB) {
    int r = row + (lane & 15);
    int off = r * SB + ((k + ((lane >> 4) << 3)) << 1);
    off ^= (r & 7) << 4;
    return *(const short8v*)((const char*)lds + off);
}

// Stage a 128x256 bf16 tile (row-major, rowstride elems) into swizzled LDS (rowbytes 512).
__device__ __forceinline__ void stage128x256(const u16* __restrict__ g, int row0, int rowmax,
                                             int rowstride, int col0, u16* lds, int tid) {
    #pragma unroll
    for (int it = 0; it < 16; ++it) {
        int chunk = tid + it * 256;
        int r = chunk >> 5;
        int kc = (chunk & 31) << 3;
        short8v v = {0, 0, 0, 0, 0, 0, 0, 0};
        if (row0 + r < rowmax)
            v = *(const short8v*)(g + (size_t)(row0 + r) * rowstride + col0 + kc);
        int off = (r * 512 + kc * 2) ^ ((r & 7) << 4);
        *(short8v*)((char*)lds + off) = v;
    }
}

// ---------------- setup kernels ----------------

__global__ __launch_bounds__(256) void k_wpbf(const float* __restrict__ Wf,
                                              const float* __restrict__ Wb,
                                              u16* __restrict__ out) {
    int chunk = blockIdx.x * 256 + threadIdx.x;   // 2*8000*32 = 512000
    int kc = (chunk & 31) << 3;
    int v = (chunk >> 5) % 8000;
    int d = chunk / (8000 * 32);
    const float* src = (d ? Wb : Wf) + (size_t)v * 256 + kc;
    u16 t8[8];
    #pragma unroll
    for (int j = 0; j < 8; ++j) t8[j] = f2bf(src[j]);
    *(short8v*)(out + ((size_t)d * 8000 + v) * 256 + kc) = *(short8v*)t8;
}

// WdecBF[d][r][k]: k<256 -> Whh[r][k], else Wih[r][k-256]
__global__ __launch_bounds__(256) void k_wdecbf(const float* __restrict__ fWhh, const float* __restrict__ fWih,
                                                const float* __restrict__ bWhh, const float* __restrict__ bWih,
                                                u16* __restrict__ out) {
    int chunk = blockIdx.x * 256 + threadIdx.x;   // 2*1024*64 = 131072
    int kc = (chunk & 63) << 3;
    int r = (chunk >> 6) & 1023;
    int d = chunk >> 16;
    const float* Whh = d ? bWhh : fWhh;
    const float* Wih = d ? bWih : fWih;
    const float* src = (kc < 256) ? (Whh + (size_t)r * 256 + kc) : (Wih + (size_t)r * 256 + (kc - 256));
    u16 t8[8];
    #pragma unroll
    for (int j = 0; j < 8; ++j) t8[j] = f2bf(src[j]);
    *(short8v*)(out + ((size_t)d * 1024 + r) * 512 + kc) = *(short8v*)t8;
}

// encW[r][k]: k<256 -> enc_Whh[r][k], else enc_Wih[r][k-256]  (Wih half used by k_xproj)
__global__ __launch_bounds__(256) void k_wencbf(const float* __restrict__ Whh, const float* __restrict__ Wih,
                                                u16* __restrict__ out) {
    int chunk = blockIdx.x * 256 + threadIdx.x;   // 1024*64 = 65536
    int kc = (chunk & 63) << 3;
    int r = chunk >> 6;
    const float* src = (kc < 256) ? (Whh + (size_t)r * 256 + kc) : (Wih + (size_t)r * 256 + (kc - 256));
    u16 t8[8];
    #pragma unroll
    for (int j = 0; j < 8; ++j) t8[j] = f2bf(src[j]);
    *(short8v*)(out + (size_t)r * 512 + kc) = *(short8v*)t8;
}

// per-row scales for enc Whh int8 quantization
__global__ __launch_bounds__(256) void k_escale(const float* __restrict__ Whh,
                                                float* __restrict__ s_enc,
                                                float* __restrict__ sq) {
    int r = blockIdx.x * 256 + threadIdx.x;
    if (r >= 1024) return;
    float m = 0.0f;
    for (int k = 0; k < 256; ++k) m = fmaxf(m, fabsf(Whh[r * 256 + k]));
    s_enc[r] = m / 16129.0f;            // m/(127*127): dequant (folds h scale 1/127)
    sq[r] = (m > 0.0f) ? 127.0f / m : 0.0f;
}

// wq for k_enc5: lin = (((w*4+c)*4+ks)*64+lane) ->
// gate-row r = c*256 + w*16 + (lane&15), k = ks*64 + (lane>>4)*16 .. +16
__global__ __launch_bounds__(256) void k_wq2(const float* __restrict__ Whh,
                                             const float* __restrict__ sq,
                                             signed char* __restrict__ wq) {
    int lin = blockIdx.x * 256 + threadIdx.x;   // 16*4*4*64 = 16384
    int lane = lin & 63;
    int ks = (lin >> 6) & 3;
    int c = (lin >> 8) & 3;
    int w = lin >> 10;
    int r = c * 256 + w * 16 + (lane & 15);
    int kb = ks * 64 + ((lane >> 4) << 4);
    float s = sq[r];
    signed char o16[16];
    #pragma unroll
    for (int j = 0; j < 16; ++j) {
        float q = rintf(Whh[r * 256 + kb + j] * s);
        q = fminf(127.0f, fmaxf(-127.0f, q));
        o16[j] = (signed char)q;
    }
    *(int4v*)(wq + (size_t)lin * 16) = *(int4v*)o16;
}

// xEncBF[d][t][b][k] = bf16(emb[tok]), tok = t==0 ? 0 : (fwd S[b][t-1] / bwd S[b][128-t])
__global__ __launch_bounds__(256) void k_xenc(const int* __restrict__ S, const float* __restrict__ emb,
                                              u16* __restrict__ out) {
    int chunk = blockIdx.x * 256 + threadIdx.x;   // 2*128*16*32 = 131072
    int kc = (chunk & 31) << 3;
    int b = (chunk >> 5) & 15;
    int t = (chunk >> 9) & 127;
    int d = chunk >> 16;
    int tok = 0;
    if (t > 0) tok = d ? S[b * 128 + 128 - t] : S[b * 128 + t - 1];
    const float* src = emb + (size_t)tok * 256 + kc;
    u16 t8[8];
    #pragma unroll
    for (int j = 0; j < 8; ++j) t8[j] = f2bf(src[j]);
    *(short8v*)(out + (size_t)(((d * 128 + t) * 16) + b) * 256 + kc) = *(short8v*)t8;
}

__global__ __launch_bounds__(256) void k_decx(const int* __restrict__ S, const float* __restrict__ emb,
                                              u16* __restrict__ decX, int* __restrict__ winTok) {
    int chunk = blockIdx.x * 256 + threadIdx.x;   // 2*3*2048*32 = 393216
    int kc = (chunk & 31) << 3;
    int n = (chunk >> 5) & 2047;
    int r2 = chunk >> 16;
    int s = r2 % 3, d = r2 / 3;
    int b = n >> 7, tq = n & 127;
    int pos = min(tq + s, 127);
    int tok = d ? S[b * 128 + 127 - pos] : S[b * 128 + pos];
    const float* src = emb + (size_t)tok * 256 + kc;
    u16 t8[8];
    #pragma unroll
    for (int j = 0; j < 8; ++j) t8[j] = f2bf(src[j]);
    *(short8v*)(decX + ((size_t)(d * 3 + s) * NN + n) * 256 + kc) = *(short8v*)t8;
    if ((chunk & 31) == 0) winTok[(d * 3 + s) * NN + n] = tok;
}

// xp0[d][r] = emb[PART=0] . dec_Wih_d[r]  (f32, exact)
__global__ __launch_bounds__(256) void k_xp0(const float* __restrict__ emb,
                                             const float* __restrict__ Wihf,
                                             const float* __restrict__ Wihb,
                                             float* __restrict__ xp0) {
    int idx = blockIdx.x * 256 + threadIdx.x;  // 2048
    int d = idx >> 10, r = idx & 1023;
    const float* Wih = d ? Wihb : Wihf;
    float acc = 0.0f;
    for (int k = 0; k < 256; ++k) acc = fmaf(emb[k], Wih[r * 256 + k], acc);
    xp0[idx] = acc;
}

// ---------------- encoder x-projection GEMM -> k_enc5 layout ----------------
__global__ __launch_bounds__(256) void k_xproj(const u16* __restrict__ xEncBF,
                                               const u16* __restrict__ encW,
                                               const float* __restrict__ ebih,
                                               const float* __restrict__ ebhh,
                                               float* __restrict__ xpT) {
    __shared__ u16 At[128 * 256];
    __shared__ u16 Bt[128 * 256];
    const int tid = threadIdx.x, lane = tid & 63, wid = tid >> 6;
    const int wm = wid >> 1, wv = wid & 1;
    const int r0 = blockIdx.x * 128, n0 = blockIdx.y * 128, d = blockIdx.z;
    stage128x256(xEncBF + (size_t)d * 2048 * 256, n0, 1 << 30, 256, 0, At, tid);
    stage128x256(encW, r0, 1 << 30, 512, 256, Bt, tid);
    __syncthreads();
    float4v acc[4][4];
    #pragma unroll
    for (int m = 0; m < 4; ++m)
        #pragma unroll
        for (int v = 0; v < 4; ++v) acc[m][v] = (float4v){0.f, 0.f, 0.f, 0.f};
    #pragma unroll
    for (int k = 0; k < 8; ++k) {
        short8v af[4], bf[4];
        #pragma unroll
        for (int m = 0; m < 4; ++m) af[m] = ldfrag(At, wm * 64 + m * 16, k * 32, lane, 512);
        #pragma unroll
        for (int v = 0; v < 4; ++v) bf[v] = ldfrag(Bt, wv * 64 + v * 16, k * 32, lane, 512);
        #pragma unroll
        for (int m = 0; m < 4; ++m)
            #pragma unroll
            for (int v = 0; v < 4; ++v)
                acc[m][v] = __builtin_amdgcn_mfma_f32_16x16x32_bf16(af[m], bf[v], acc[m][v], 0, 0, 0);
    }
    float bs[4]; int rg[4];
    #pragma unroll
    for (int v = 0; v < 4; ++v) {
        rg[v] = r0 + wv * 64 + v * 16 + (lane & 15);
        bs[v] = ebih[rg[v]] + ebhh[rg[v]];
    }
    #pragma unroll
    for (int m = 0; m < 4; ++m)
        #pragma unroll
        for (int i = 0; i < 4; ++i) {
            int n = n0 + wm * 64 + m * 16 + ((lane >> 4) << 2) + i;
            int t_ = n >> 4, bfull = n & 15;
            #pragma unroll
            for (int v = 0; v < 4; ++v) {
                int g = rg[v] >> 8, u = rg[v] & 255;
                size_t idx4 = (((size_t)(d * 16 + bfull) * 128 + t_) * 16 + (u >> 4)) * 16 + (u & 15);
                xpT[idx4 * 4 + g] = acc[m][v][i] + bs[v];
            }
        }
}

// ---------------- encoder: 1 batch/block (32 blocks), swizzled hbuf, pipelined xv ----------
__global__ __launch_bounds__(1024) void k_enc5(const signed char* __restrict__ wq,
                                               const float* __restrict__ s_enc,
                                               const float4v* __restrict__ xpT4,
                                               u16* __restrict__ h0bf) {
    __shared__ signed char hbuf[2][4096];    // [16 rows][256 u] int8, XOR-swizzled; row 0 live
    const int tid = threadIdx.x, lane = tid & 63, w = tid >> 6;   // w in [0,16)
    const int blk = blockIdx.x, d = blk >> 4, b = blk & 15;
    const int l15 = lane & 15, hi = lane >> 4;
    int4v breg[4][4];
    #pragma unroll
    for (int c = 0; c < 4; ++c)
        #pragma unroll
        for (int ks = 0; ks < 4; ++ks)
            breg[c][ks] = *(const int4v*)(wq + ((size_t)(((w * 4 + c) * 4 + ks) * 64 + lane)) * 16);
    float sreg[4];
    #pragma unroll
    for (int c = 0; c < 4; ++c) sreg[c] = s_enc[c * 256 + w * 16 + l15];
    float creg = 0.0f;
    ((long*)hbuf)[tid] = 0l;
    const bool cellane = (lane < 16);
    const int u = w * 16 + l15;
    const float4v* xbase = xpT4 + ((size_t)(d * 16 + b) * 128) * 256 + w * 16 + l15;
    float4v xv_next = {0.f, 0.f, 0.f, 0.f};
    if (cellane) xv_next = xbase[0];
    __syncthreads();
    for (int t = 0; t < 128; ++t) {
        int cur = t & 1;
        float4v xv = xv_next;
        if (cellane && t < 127) xv_next = xbase[(size_t)(t + 1) * 256];
        int4v af[4];
        #pragma unroll
        for (int ks = 0; ks < 4; ++ks) {
            int off = (l15 * 256 + ks * 64 + hi * 16) ^ ((l15 & 7) << 4);
            af[ks] = *(const int4v*)(hbuf[cur] + off);
        }
        int4v acc[4];
        #pragma unroll
        for (int c = 0; c < 4; ++c) {
            acc[c] = (int4v){0, 0, 0, 0};
            #pragma unroll
            for (int ks = 0; ks < 4; ++ks)
                acc[c] = __builtin_amdgcn_mfma_i32_16x16x64_i8(af[ks], breg[c][ks], acc[c], 0, 0, 0);
        }
        if (cellane) {
            float gi = (float)acc[0][0] * sreg[0] + xv[0];
            float gf = (float)acc[1][0] * sreg[1] + xv[1];
            float gG = (float)acc[2][0] * sreg[2] + xv[2];
            float go = (float)acc[3][0] * sreg[3] + xv[3];
            float cn = sigf(gf) * creg + sigf(gi) * tanhsafe(gG);
            float h = sigf(go) * tanhsafe(cn);
            creg = cn;
            h0bf[((size_t)d * NN + b * 128 + t) * 256 + u] = f2bf(h);
            hbuf[cur ^ 1][u] = (signed char)rintf(h * 127.0f);   // row 0: swizzle mask = 0
        }
        __syncthreads();
    }
}

// ---------------- decoder gate GEMM (MFMA, 128x128 tile, K phases) ----------------
__global__ __launch_bounds__(256) void k_decmm(const u16* __restrict__ Ah, size_t ahStride,
                                               const u16* __restrict__ Axx, size_t axStride,
                                               const u16* __restrict__ Wdec,
                                               const float* __restrict__ bihf, const float* __restrict__ bhhf,
                                               const float* __restrict__ bihb, const float* __restrict__ bhhb,
                                               const float* __restrict__ xp0, int useX,
                                               float* __restrict__ gBuf) {
    __shared__ u16 At[128 * 256];
    __shared__ u16 Bt[128 * 256];
    const int tid = threadIdx.x, lane = tid & 63, wid = tid >> 6;
    const int wm = wid >> 1, wv = wid & 1;
    const int r0 = blockIdx.x * 128, n0 = blockIdx.y * 128, d = blockIdx.z;
    float4v acc[4][4];
    #pragma unroll
    for (int m = 0; m < 4; ++m)
        #pragma unroll
        for (int v = 0; v < 4; ++v) acc[m][v] = (float4v){0.f, 0.f, 0.f, 0.f};
    const int nph = useX ? 2 : 1;
    for (int ph = 0; ph < nph; ++ph) {
        const u16* Asrc = (ph == 0) ? (Ah + (size_t)d * ahStride) : (Axx + (size_t)d * axStride);
        stage128x256(Asrc, n0, 1 << 30, 256, 0, At, tid);
        stage128x256(Wdec + (size_t)d * 1024 * 512, r0, 1 << 30, 512, ph * 256, Bt, tid);
        __syncthreads();
        #pragma unroll
        for (int k = 0; k < 8; ++k) {
            short8v af[4], bf[4];
            #pragma unroll
            for (int m = 0; m < 4; ++m) af[m] = ldfrag(At, wm * 64 + m * 16, k * 32, lane, 512);
            #pragma unroll
            for (int v = 0; v < 4; ++v) bf[v] = ldfrag(Bt, wv * 64 + v * 16, k * 32, lane, 512);
            #pragma unroll
            for (int m = 0; m < 4; ++m)
                #pragma unroll
                for (int v = 0; v < 4; ++v)
                    acc[m][v] = __builtin_amdgcn_mfma_f32_16x16x32_bf16(af[m], bf[v], acc[m][v], 0, 0, 0);
        }
        __syncthreads();
    }
    const float* bih = d ? bihb : bihf;
    const float* bhh = d ? bhhb : bhhf;
    float bs[4]; int rg[4];
    #pragma unroll
    for (int v = 0; v < 4; ++v) {
        rg[v] = r0 + wv * 64 + v * 16 + (lane & 15);
        bs[v] = bih[rg[v]] + bhh[rg[v]];
        if (!useX) bs[v] += xp0[d * 1024 + rg[v]];
    }
    #pragma unroll
    for (int m = 0; m < 4; ++m)
        #pragma unroll
        for (int i = 0; i < 4; ++i) {
            int n = n0 + wm * 64 + m * 16 + ((lane >> 4) << 2) + i;
            #pragma unroll
            for (int v = 0; v < 4; ++v)
                gBuf[((size_t)d * NN + n) * 1024 + rg[v]] = acc[m][v][i] + bs[v];
        }
}

// ---------------- decoder cell ----------------
__global__ __launch_bounds__(256) void k_deccell(const float* __restrict__ gBuf,
                                                 const u16* __restrict__ h0bf,
                                                 float* __restrict__ cDec,
                                                 u16* __restrict__ hsBF, int s) {
    int flat = blockIdx.x * 256 + threadIdx.x;  // 2*2048*256
    int j = flat & 255;
    int n = (flat >> 8) & 2047;
    int d = flat >> 19;
    const float* g = gBuf + ((size_t)d * NN + n) * 1024;
    float gi = g[j], gf = g[j + 256], gg = g[j + 512], go = g[j + 768];
    float cprev = (s == 0) ? bf2f(h0bf[flat]) : cDec[flat];
    float cn = sigf(gf) * cprev + sigf(gi) * tanhsafe(gg);
    float h = sigf(go) * tanhsafe(cn);
    cDec[flat] = cn;
    hsBF[((size_t)(d * 4 + s) * NN + n) * 256 + j] = f2bf(h);
}

// ---------------- projection v6: B global->register (no mid-loop barriers), A-resident ----
// Grid 256 flat: xcd=L&7 -> chunkI (B slice L2-resident per XCD); idx=L>>3: n0=(idx&15)*128,
// d=idx>>4. 8 waves = 4 row-groups x 2 col-groups. No-max expsum (logits bounded).
// B fragment loads are fully coalesced: wave reads rows vt*64+wv*32+v*16+{0..15},
// bytes [64kk,64kk+64) = 16 x 64B segments. L1 absorbs the 4x wm-wave redundancy.
__global__ __launch_bounds__(512, 2) void k_proj6(const u16* __restrict__ hsBF,
                                                  const u16* __restrict__ WpBF,
                                                  const float* __restrict__ bpf, const float* __restrict__ bpb,
                                                  const int* __restrict__ winTok,
                                                  float* __restrict__ partials,
                                                  float* __restrict__ gchar, float* __restrict__ gtag) {
    __shared__ u16 At[128 * 256];        // 64KB, full K, swizzled (rowbytes 512)
    const int tid = threadIdx.x, lane = tid & 63, w = tid >> 6;
    const int wm = w >> 1, wv = w & 1;   // 4 row-groups x 2 col-groups
    const int l15 = lane & 15, hi = lane >> 4;
    const int L = blockIdx.x;
    const int chunkI = L & 7, idx = L >> 3;
    const int n0 = (idx & 15) * 128, d = idx >> 4;
    const int vt0 = chunkI * 16;
    const int nvt = min(16, 125 - vt0);  // 125 x 64 = 8000 v-cols exact
    const float* bp = d ? bpb : bpf;
    const u16* WpD = WpBF + (size_t)d * 8000 * 256;

    for (int s = 0; s < 4; ++s) {
        __syncthreads();                 // prev-s At readers done
        // stage A(s): 128 rows x 256 k, swizzled
        const u16* hsA = hsBF + (size_t)(d * 4 + s) * NN * 256;
        #pragma unroll
        for (int it = 0; it < 8; ++it) {
            int chunk = tid + it * 512;
            int r = chunk >> 5, kc = (chunk & 31) << 3;
            short8v v8 = *(const short8v*)(hsA + (size_t)(n0 + r) * 256 + kc);
            int off = (r * 512 + kc * 2) ^ ((r & 7) << 4);
            *(short8v*)((char*)At + off) = v8;
        }
        int tok[2][4];
        #pragma unroll
        for (int m = 0; m < 2; ++m)
            #pragma unroll
            for (int i = 0; i < 4; ++i) {
                int n = n0 + wm * 32 + m * 16 + hi * 4 + i;
                tok[m][i] = (s < 3) ? winTok[(d * 3 + s) * NN + n] : -1;
            }
        float expsum[2][4] = {{0.f, 0.f, 0.f, 0.f}, {0.f, 0.f, 0.f, 0.f}};
        __syncthreads();                 // At visible
        for (int t = 0; t < nvt; ++t) {
            int vt = vt0 + t;
            float bpv[2];
            #pragma unroll
            for (int v = 0; v < 2; ++v) bpv[v] = bp[vt * 64 + wv * 32 + v * 16 + l15];
            float4v acc[2][2];
            #pragma unroll
            for (int m = 0; m < 2; ++m)
                #pragma unroll
                for (int v = 0; v < 2; ++v) acc[m][v] = (float4v){0.f, 0.f, 0.f, 0.f};
            #pragma unroll
            for (int kk = 0; kk < 8; ++kk) {
                short8v af[2], bf[2];
                #pragma unroll
                for (int v = 0; v < 2; ++v)
                    bf[v] = *(const short8v*)(WpD +
                        (size_t)(vt * 64 + wv * 32 + v * 16 + l15) * 256 + kk * 32 + hi * 8);
                #pragma unroll
                for (int m = 0; m < 2; ++m) af[m] = ldfrag(At, wm * 32 + m * 16, kk * 32, lane, 512);
                #pragma unroll
                for (int m = 0; m < 2; ++m)
                    #pragma unroll
                    for (int v = 0; v < 2; ++v)
                        acc[m][v] = __builtin_amdgcn_mfma_f32_16x16x32_bf16(af[m], bf[v], acc[m][v], 0, 0, 0);
            }
            // light epilogue: exp-accumulate + capture (no max: logits bounded)
            #pragma unroll
            for (int m = 0; m < 2; ++m)
                #pragma unroll
                for (int i = 0; i < 4; ++i) {
                    int n = n0 + wm * 32 + m * 16 + hi * 4 + i;
                    float es = 0.0f;
                    #pragma unroll
                    for (int v = 0; v < 2; ++v) {
                        int vgv = vt * 64 + wv * 32 + v * 16 + l15;
                        float lg = acc[m][v][i] + bpv[v];
                        es += __expf(lg);
                        if (vgv == tok[m][i]) gchar[(d * 3 + s) * NN + n] = lg;
                        if (s >= 1 && vgv == 0) gtag[(d * 3 + (s - 1)) * NN + n] = lg;
                    }
                    expsum[m][i] += es;
                }
        }
        // reduce expsum across the 16 l15 lanes sharing each row; per-(chunk,wv) slot
        #pragma unroll
        for (int m = 0; m < 2; ++m)
            #pragma unroll
            for (int i = 0; i < 4; ++i) {
                float e = expsum[m][i];
                #pragma unroll
                for (int off = 1; off <= 8; off <<= 1) e += __shfl_xor(e, off);
                if (l15 == 0) {
                    int n = n0 + wm * 32 + m * 16 + hi * 4 + i;
                    partials[((size_t)(d * 4 + s) * NN + n) * 16 + chunkI * 2 + wv] = e;
                }
            }
    }
}

// ---------------- logZ = log(sum of 16 partials) ----------------
__global__ __launch_bounds__(256) void k_lzsum(const float* __restrict__ partials,
                                               float* __restrict__ logZ) {
    int row = blockIdx.x * 256 + threadIdx.x;  // 16384
    const float* p = partials + (size_t)row * 16;
    float s = 0.0f;
    #pragma unroll
    for (int c = 0; c < 16; ++c) s += p[c];
    logZ[row] = __logf(s);
}

// ---------------- P assembly ----------------
__global__ __launch_bounds__(256) void k_passm(const float* __restrict__ gchar,
                                               const float* __restrict__ gtag,
                                               const float* __restrict__ logZ,
                                               float* __restrict__ P) {
    int flat = blockIdx.x * 256 + threadIdx.x;  // 128*3*16
    if (flat >= 128 * 3 * 16) return;
    int b = flat & 15;
    int y = (flat >> 4) % 3;
    int x = flat / 48;
    int nf = b * 128 + min(127, max(0, x - y));
    int nb = b * 128 + 127 - x;
    float pf = 0.0f, pb = 0.0f;
    for (int ss = 0; ss <= y; ++ss) {
        pf += gchar[ss * NN + nf] - logZ[ss * NN + nf];
        pb += gchar[(3 + ss) * NN + nb] - logZ[(4 + ss) * NN + nb];
    }
    pf += gtag[y * NN + nf] - logZ[(y + 1) * NN + nf];
    pb += gtag[(3 + y) * NN + nb] - logZ[(4 + y + 1) * NN + nb];
    P[flat] = 0.5f * (pf + pb);
}

// ---------------- semi-CRF scan + loss: single wave, P in LDS, zero barriers in loop ----------
__global__ __launch_bounds__(64) void k_scan(const float* __restrict__ P, float* __restrict__ out) {
    __shared__ float Pl[128 * 48];
    int tid = threadIdx.x;
    #pragma unroll
    for (int it = 0; it < 96; ++it) Pl[tid + it * 64] = P[tid + it * 64];
    __syncthreads();   // one wave: cheap; ensures LDS visible
    if (tid < 16) {
        int b = tid;
        float b0 = 0.f, b1 = 0.f, b2 = 0.f, tot = 0.f;
        for (int j = 1; j <= 128; ++j) {
            float c0 = b0 + Pl[((j - 1) * 3 + 0) * 16 + b];
            float c1 = (j >= 2) ? b1 + Pl[((j - 1) * 3 + 1) * 16 + b] : -1e30f;
            float c2 = (j >= 3) ? b2 + Pl[((j - 1) * 3 + 2) * 16 + b] : -1e30f;
            float mx = fmaxf(c0, fmaxf(c1, c2));
            float sv = __expf(c0 - mx) + __expf(c1 - mx) + __expf(c2 - mx);
            tot = mx + __logf(sv);
            b2 = b1; b1 = b0; b0 = tot;
        }
        #pragma unroll
        for (int off = 1; off <= 8; off <<= 1) tot += __shfl_xor(tot, off);
        if (b == 0) out[0] = -tot / 16.0f;
    }
}

// ---------------- launch ----------------
extern "C" void kernel_launch(void* const* d_in, const int* in_sizes, int n_in,
                              void* d_out, int out_size, void* d_ws, size_t ws_size,
                              hipStream_t stream) {
    const int* S = (const int*)d_in[0];
    const float* emb = (const float*)d_in[1];
    const float* eWih = (const float*)d_in[2];
    const float* eWhh = (const float*)d_in[3];
    const float* ebih = (const float*)d_in[4];
    const float* ebhh = (const float*)d_in[5];
    const float* fWih = (const float*)d_in[6];
    const float* fWhh = (const float*)d_in[7];
    const float* fbih = (const float*)d_in[8];
    const float* fbhh = (const float*)d_in[9];
    const float* fWp  = (const float*)d_in[10];
    const float* fbp  = (const float*)d_in[11];
    const float* bWih = (const float*)d_in[12];
    const float* bWhh = (const float*)d_in[13];
    const float* bbih = (const float*)d_in[14];
    const float* bbhh = (const float*)d_in[15];
    const float* bWp  = (const float*)d_in[16];
    const float* bbp  = (const float*)d_in[17];

    float* w = (float*)d_ws;
    u16* WpBF    = (u16*)(w + OFF_WPBF);
    u16* WdecBF  = (u16*)(w + OFF_WDEC);
    u16* xEncBF  = (u16*)(w + OFF_XENC);
    u16* h0bf    = (u16*)(w + OFF_H0BF);
    u16* decXBF  = (u16*)(w + OFF_DECX);
    float* cDec  = w + OFF_CDEC;
    u16* hsBF    = (u16*)(w + OFF_HSBF);
    float* gBuf  = w + OFF_GBUF;
    float* xpT   = gBuf;      // aliased: consumed by k_enc5 before decoder writes gBuf
    float* partials = gBuf;   // aliased: used only after decoder
    float* logZ  = w + OFF_LOGZ;
    float* gchar = w + OFF_GCH;
    float* gtag  = w + OFF_GTG;
    float* Pm    = w + OFF_P;
    int* winTok  = (int*)(w + OFF_WTOK);
    float* xp0   = w + OFF_XP0;
    u16* encW    = (u16*)(w + OFF_ENCW);
    float* sEnc  = w + OFF_SENC;
    float* sQ    = w + OFF_SQ;
    signed char* wqEnc = (signed char*)(w + OFF_WQI8);

    k_wpbf<<<2000, 256, 0, stream>>>(fWp, bWp, WpBF);
    k_wdecbf<<<512, 256, 0, stream>>>(fWhh, fWih, bWhh, bWih, WdecBF);
    k_wencbf<<<256, 256, 0, stream>>>(eWhh, eWih, encW);
    k_escale<<<4, 256, 0, stream>>>(eWhh, sEnc, sQ);
    k_wq2<<<64, 256, 0, stream>>>(eWhh, sQ, wqEnc);
    k_xenc<<<512, 256, 0, stream>>>(S, emb, xEncBF);
    k_decx<<<1536, 256, 0, stream>>>(S, emb, decXBF, winTok);
    k_xp0<<<8, 256, 0, stream>>>(emb, fWih, bWih, xp0);

    k_xproj<<<dim3(8, 16, 2), 256, 0, stream>>>(xEncBF, encW, ebih, ebhh, xpT);
    k_enc5<<<32, 1024, 0, stream>>>(wqEnc, sEnc, (const float4v*)xpT, h0bf);

    for (int s = 0; s < 4; ++s) {
        const u16* Ah; size_t ahS;
        const u16* Axx; size_t axS;
        if (s == 0) {
            Ah = h0bf; ahS = (size_t)NN * 256;
            Axx = decXBF; axS = (size_t)3 * NN * 256;  // unused
        } else {
            Ah = hsBF + (size_t)(s - 1) * NN * 256; ahS = (size_t)4 * NN * 256;
            Axx = decXBF + (size_t)(s - 1) * NN * 256; axS = (size_t)3 * NN * 256;
        }
        k_decmm<<<dim3(8, 16, 2), 256, 0, stream>>>(Ah, ahS, Axx, axS, WdecBF,
                                                    fbih, fbhh, bbih, bbhh, xp0,
                                                    (s == 0) ? 0 : 1, gBuf);
        k_deccell<<<4096, 256, 0, stream>>>(gBuf, h0bf, cDec, hsBF, s);
    }

    k_proj6<<<256, 512, 0, stream>>>(hsBF, WpBF, fbp, bbp, winTok,
                                     partials, gchar, gtag);
    k_lzsum<<<64, 256, 0, stream>>>(partials, logZ);
    k_passm<<<24, 256, 0, stream>>>(gchar, gtag, logZ, Pm);
    k_scan<<<1, 64, 0, stream>>>(Pm, (float*)d_out);
}

// Round 15
// 514.214 us; speedup vs baseline: 1.2791x; 1.2791x over previous
//
#include <hip/hip_runtime.h>
#include <math.h>

#define VOCAB 8000
#define NN 2048   /* B*T */

typedef unsigned short u16;
typedef __attribute__((ext_vector_type(8))) short short8v;
typedef __attribute__((ext_vector_type(4))) short short4v;
typedef __attribute__((ext_vector_type(4))) float float4v;
typedef __attribute__((ext_vector_type(4))) int int4v;

// ---- workspace offsets (in float slots) ----
#define OFF_WPBF   0ul          /* bf16 [2][8000][256]      2,048,000 */
#define OFF_WDEC   2048000ul    /* bf16 [2][1024][512]        524,288 */
#define OFF_XENC   2572288ul    /* bf16 [2][128][16][256]     524,288 */
#define OFF_H0BF   4153344ul    /* bf16 [2][2048][256]        524,288 */
#define OFF_DECX   4677632ul    /* bf16 [2][3][2048][256]   1,572,864 */
#define OFF_CDEC   6250496ul    /* f32  [2][2048][256]      1,048,576 */
#define OFF_HSBF   7299072ul    /* bf16 [8][2048][256]      2,097,152 */
#define OFF_GBUF   9396224ul    /* f32  4,194,304 (aliased: xpT, then decoder gBuf, then partials[16384][16]) */
#define OFF_LOGZ   13590528ul   /* f32  [8][2048]              16,384 */
#define OFF_GCH    13606912ul   /* f32  [2][3][2048]           12,288 */
#define OFF_GTG    13619200ul   /* f32  [2][3][2048]           12,288 */
#define OFF_P      13631488ul   /* f32  [128][3][16]            6,144 */
#define OFF_WTOK   13637632ul   /* int  [2][3][2048]           12,288 */
#define OFF_XP0    13649920ul   /* f32  [2][1024]               2,048 */
#define OFF_ENCW   13652032ul   /* bf16 [1024][512]           262,144 */
#define OFF_SENC   13914240ul   /* f32  [1024] dequant scale    1,024 */
#define OFF_SQ     13915264ul   /* f32  [1024] quant scale      1,024 */
#define OFF_WQI8   13916288ul   /* i8   [16384][16]            65,536 f32 slots */

__device__ __forceinline__ float sigf(float x) { return 1.0f / (1.0f + __expf(-x)); }
__device__ __forceinline__ float tanhsafe(float x) {
    x = fminf(15.0f, fmaxf(-15.0f, x));
    float e = __expf(2.0f * x);
    return (e - 1.0f) / (e + 1.0f);
}
__device__ __forceinline__ u16 f2bf(float f) {
    union { float f; unsigned int u; } x; x.f = f;
    return (u16)((x.u + 0x7fffu + ((x.u >> 16) & 1u)) >> 16);
}
__device__ __forceinline__ float bf2f(u16 x) {
    union { unsigned int u; float f; } v; v.u = ((unsigned int)x) << 16;
    return v.f;
}

// MFMA fragment load from a swizzled LDS tile (bf16). Rows of SB bytes; lane l reads
// row (row + (l&15)), 8 contiguous bf16 at k + (l>>4)*8. XOR swizzle (r&7)<<4.
__device__ __forceinline__ short8v ldfrag(const u16* lds, int row, int k, int lane, int SB) {
    int r = row + (lane & 15);
    int off = r * SB + ((k + ((lane >> 4) << 3)) << 1);
    off ^= (r & 7) << 4;
    return *(const short8v*)((const char*)lds + off);
}

// Stage a 128x256 bf16 tile (row-major, rowstride elems) into swizzled LDS (rowbytes 512).
__device__ __forceinline__ void stage128x256(const u16* __restrict__ g, int row0, int rowmax,
                                             int rowstride, int col0, u16* lds, int tid) {
    #pragma unroll
    for (int it = 0; it < 16; ++it) {
        int chunk = tid + it * 256;
        int r = chunk >> 5;
        int kc = (chunk & 31) << 3;
        short8v v = {0, 0, 0, 0, 0, 0, 0, 0};
        if (row0 + r < rowmax)
            v = *(const short8v*)(g + (size_t)(row0 + r) * rowstride + col0 + kc);
        int off = (r * 512 + kc * 2) ^ ((r & 7) << 4);
        *(short8v*)((char*)lds + off) = v;
    }
}

// ---------------- setup kernels ----------------

__global__ __launch_bounds__(256) void k_wpbf(const float* __restrict__ Wf,
                                              const float* __restrict__ Wb,
                                              u16* __restrict__ out) {
    int chunk = blockIdx.x * 256 + threadIdx.x;   // 2*8000*32 = 512000
    int kc = (chunk & 31) << 3;
    int v = (chunk >> 5) % 8000;
    int d = chunk / (8000 * 32);
    const float* src = (d ? Wb : Wf) + (size_t)v * 256 + kc;
    u16 t8[8];
    #pragma unroll
    for (int j = 0; j < 8; ++j) t8[j] = f2bf(src[j]);
    *(short8v*)(out + ((size_t)d * 8000 + v) * 256 + kc) = *(short8v*)t8;
}

// WdecBF[d][r][k]: k<256 -> Whh[r][k], else Wih[r][k-256]
__global__ __launch_bounds__(256) void k_wdecbf(const float* __restrict__ fWhh, const float* __restrict__ fWih,
                                                const float* __restrict__ bWhh, const float* __restrict__ bWih,
                                                u16* __restrict__ out) {
    int chunk = blockIdx.x * 256 + threadIdx.x;   // 2*1024*64 = 131072
    int kc = (chunk & 63) << 3;
    int r = (chunk >> 6) & 1023;
    int d = chunk >> 16;
    const float* Whh = d ? bWhh : fWhh;
    const float* Wih = d ? bWih : fWih;
    const float* src = (kc < 256) ? (Whh + (size_t)r * 256 + kc) : (Wih + (size_t)r * 256 + (kc - 256));
    u16 t8[8];
    #pragma unroll
    for (int j = 0; j < 8; ++j) t8[j] = f2bf(src[j]);
    *(short8v*)(out + ((size_t)d * 1024 + r) * 512 + kc) = *(short8v*)t8;
}

// encW[r][k]: k<256 -> enc_Whh[r][k], else enc_Wih[r][k-256]  (Wih half used by k_xproj)
__global__ __launch_bounds__(256) void k_wencbf(const float* __restrict__ Whh, const float* __restrict__ Wih,
                                                u16* __restrict__ out) {
    int chunk = blockIdx.x * 256 + threadIdx.x;   // 1024*64 = 65536
    int kc = (chunk & 63) << 3;
    int r = chunk >> 6;
    const float* src = (kc < 256) ? (Whh + (size_t)r * 256 + kc) : (Wih + (size_t)r * 256 + (kc - 256));
    u16 t8[8];
    #pragma unroll
    for (int j = 0; j < 8; ++j) t8[j] = f2bf(src[j]);
    *(short8v*)(out + (size_t)r * 512 + kc) = *(short8v*)t8;
}

// per-row scales for enc Whh int8 quantization
__global__ __launch_bounds__(256) void k_escale(const float* __restrict__ Whh,
                                                float* __restrict__ s_enc,
                                                float* __restrict__ sq) {
    int r = blockIdx.x * 256 + threadIdx.x;
    if (r >= 1024) return;
    float m = 0.0f;
    for (int k = 0; k < 256; ++k) m = fmaxf(m, fabsf(Whh[r * 256 + k]));
    s_enc[r] = m / 16129.0f;            // m/(127*127): dequant (folds h scale 1/127)
    sq[r] = (m > 0.0f) ? 127.0f / m : 0.0f;
}

// wq for k_enc5: lin = (((w*4+c)*4+ks)*64+lane) ->
// gate-row r = c*256 + w*16 + (lane&15), k = ks*64 + (lane>>4)*16 .. +16
__global__ __launch_bounds__(256) void k_wq2(const float* __restrict__ Whh,
                                             const float* __restrict__ sq,
                                             signed char* __restrict__ wq) {
    int lin = blockIdx.x * 256 + threadIdx.x;   // 16*4*4*64 = 16384
    int lane = lin & 63;
    int ks = (lin >> 6) & 3;
    int c = (lin >> 8) & 3;
    int w = lin >> 10;
    int r = c * 256 + w * 16 + (lane & 15);
    int kb = ks * 64 + ((lane >> 4) << 4);
    float s = sq[r];
    signed char o16[16];
    #pragma unroll
    for (int j = 0; j < 16; ++j) {
        float q = rintf(Whh[r * 256 + kb + j] * s);
        q = fminf(127.0f, fmaxf(-127.0f, q));
        o16[j] = (signed char)q;
    }
    *(int4v*)(wq + (size_t)lin * 16) = *(int4v*)o16;
}

// xEncBF[d][t][b][k] = bf16(emb[tok]), tok = t==0 ? 0 : (fwd S[b][t-1] / bwd S[b][128-t])
__global__ __launch_bounds__(256) void k_xenc(const int* __restrict__ S, const float* __restrict__ emb,
                                              u16* __restrict__ out) {
    int chunk = blockIdx.x * 256 + threadIdx.x;   // 2*128*16*32 = 131072
    int kc = (chunk & 31) << 3;
    int b = (chunk >> 5) & 15;
    int t = (chunk >> 9) & 127;
    int d = chunk >> 16;
    int tok = 0;
    if (t > 0) tok = d ? S[b * 128 + 128 - t] : S[b * 128 + t - 1];
    const float* src = emb + (size_t)tok * 256 + kc;
    u16 t8[8];
    #pragma unroll
    for (int j = 0; j < 8; ++j) t8[j] = f2bf(src[j]);
    *(short8v*)(out + (size_t)(((d * 128 + t) * 16) + b) * 256 + kc) = *(short8v*)t8;
}

__global__ __launch_bounds__(256) void k_decx(const int* __restrict__ S, const float* __restrict__ emb,
                                              u16* __restrict__ decX, int* __restrict__ winTok) {
    int chunk = blockIdx.x * 256 + threadIdx.x;   // 2*3*2048*32 = 393216
    int kc = (chunk & 31) << 3;
    int n = (chunk >> 5) & 2047;
    int r2 = chunk >> 16;
    int s = r2 % 3, d = r2 / 3;
    int b = n >> 7, tq = n & 127;
    int pos = min(tq + s, 127);
    int tok = d ? S[b * 128 + 127 - pos] : S[b * 128 + pos];
    const float* src = emb + (size_t)tok * 256 + kc;
    u16 t8[8];
    #pragma unroll
    for (int j = 0; j < 8; ++j) t8[j] = f2bf(src[j]);
    *(short8v*)(decX + ((size_t)(d * 3 + s) * NN + n) * 256 + kc) = *(short8v*)t8;
    if ((chunk & 31) == 0) winTok[(d * 3 + s) * NN + n] = tok;
}

// xp0[d][r] = emb[PART=0] . dec_Wih_d[r]  (f32, exact)
__global__ __launch_bounds__(256) void k_xp0(const float* __restrict__ emb,
                                             const float* __restrict__ Wihf,
                                             const float* __restrict__ Wihb,
                                             float* __restrict__ xp0) {
    int idx = blockIdx.x * 256 + threadIdx.x;  // 2048
    int d = idx >> 10, r = idx & 1023;
    const float* Wih = d ? Wihb : Wihf;
    float acc = 0.0f;
    for (int k = 0; k < 256; ++k) acc = fmaf(emb[k], Wih[r * 256 + k], acc);
    xp0[idx] = acc;
}

// ---------------- encoder x-projection GEMM -> k_enc5 layout ----------------
__global__ __launch_bounds__(256) void k_xproj(const u16* __restrict__ xEncBF,
                                               const u16* __restrict__ encW,
                                               const float* __restrict__ ebih,
                                               const float* __restrict__ ebhh,
                                               float* __restrict__ xpT) {
    __shared__ u16 At[128 * 256];
    __shared__ u16 Bt[128 * 256];
    const int tid = threadIdx.x, lane = tid & 63, wid = tid >> 6;
    const int wm = wid >> 1, wv = wid & 1;
    const int r0 = blockIdx.x * 128, n0 = blockIdx.y * 128, d = blockIdx.z;
    stage128x256(xEncBF + (size_t)d * 2048 * 256, n0, 1 << 30, 256, 0, At, tid);
    stage128x256(encW, r0, 1 << 30, 512, 256, Bt, tid);
    __syncthreads();
    float4v acc[4][4];
    #pragma unroll
    for (int m = 0; m < 4; ++m)
        #pragma unroll
        for (int v = 0; v < 4; ++v) acc[m][v] = (float4v){0.f, 0.f, 0.f, 0.f};
    #pragma unroll
    for (int k = 0; k < 8; ++k) {
        short8v af[4], bf[4];
        #pragma unroll
        for (int m = 0; m < 4; ++m) af[m] = ldfrag(At, wm * 64 + m * 16, k * 32, lane, 512);
        #pragma unroll
        for (int v = 0; v < 4; ++v) bf[v] = ldfrag(Bt, wv * 64 + v * 16, k * 32, lane, 512);
        #pragma unroll
        for (int m = 0; m < 4; ++m)
            #pragma unroll
            for (int v = 0; v < 4; ++v)
                acc[m][v] = __builtin_amdgcn_mfma_f32_16x16x32_bf16(af[m], bf[v], acc[m][v], 0, 0, 0);
    }
    float bs[4]; int rg[4];
    #pragma unroll
    for (int v = 0; v < 4; ++v) {
        rg[v] = r0 + wv * 64 + v * 16 + (lane & 15);
        bs[v] = ebih[rg[v]] + ebhh[rg[v]];
    }
    #pragma unroll
    for (int m = 0; m < 4; ++m)
        #pragma unroll
        for (int i = 0; i < 4; ++i) {
            int n = n0 + wm * 64 + m * 16 + ((lane >> 4) << 2) + i;
            int t_ = n >> 4, bfull = n & 15;
            #pragma unroll
            for (int v = 0; v < 4; ++v) {
                int g = rg[v] >> 8, u = rg[v] & 255;
                size_t idx4 = (((size_t)(d * 16 + bfull) * 128 + t_) * 16 + (u >> 4)) * 16 + (u & 15);
                xpT[idx4 * 4 + g] = acc[m][v][i] + bs[v];
            }
        }
}

// ---------------- encoder: 1 batch/block (32 blocks), swizzled hbuf, pipelined xv ----------
__global__ __launch_bounds__(1024) void k_enc5(const signed char* __restrict__ wq,
                                               const float* __restrict__ s_enc,
                                               const float4v* __restrict__ xpT4,
                                               u16* __restrict__ h0bf) {
    __shared__ signed char hbuf[2][4096];    // [16 rows][256 u] int8, XOR-swizzled; row 0 live
    const int tid = threadIdx.x, lane = tid & 63, w = tid >> 6;   // w in [0,16)
    const int blk = blockIdx.x, d = blk >> 4, b = blk & 15;
    const int l15 = lane & 15, hi = lane >> 4;
    int4v breg[4][4];
    #pragma unroll
    for (int c = 0; c < 4; ++c)
        #pragma unroll
        for (int ks = 0; ks < 4; ++ks)
            breg[c][ks] = *(const int4v*)(wq + ((size_t)(((w * 4 + c) * 4 + ks) * 64 + lane)) * 16);
    float sreg[4];
    #pragma unroll
    for (int c = 0; c < 4; ++c) sreg[c] = s_enc[c * 256 + w * 16 + l15];
    float creg = 0.0f;
    ((long*)hbuf)[tid] = 0l;
    const bool cellane = (lane < 16);
    const int u = w * 16 + l15;
    const float4v* xbase = xpT4 + ((size_t)(d * 16 + b) * 128) * 256 + w * 16 + l15;
    float4v xv_next = {0.f, 0.f, 0.f, 0.f};
    if (cellane) xv_next = xbase[0];
    __syncthreads();
    for (int t = 0; t < 128; ++t) {
        int cur = t & 1;
        float4v xv = xv_next;
        if (cellane && t < 127) xv_next = xbase[(size_t)(t + 1) * 256];
        int4v af[4];
        #pragma unroll
        for (int ks = 0; ks < 4; ++ks) {
            int off = (l15 * 256 + ks * 64 + hi * 16) ^ ((l15 & 7) << 4);
            af[ks] = *(const int4v*)(hbuf[cur] + off);
        }
        int4v acc[4];
        #pragma unroll
        for (int c = 0; c < 4; ++c) {
            acc[c] = (int4v){0, 0, 0, 0};
            #pragma unroll
            for (int ks = 0; ks < 4; ++ks)
                acc[c] = __builtin_amdgcn_mfma_i32_16x16x64_i8(af[ks], breg[c][ks], acc[c], 0, 0, 0);
        }
        if (cellane) {
            float gi = (float)acc[0][0] * sreg[0] + xv[0];
            float gf = (float)acc[1][0] * sreg[1] + xv[1];
            float gG = (float)acc[2][0] * sreg[2] + xv[2];
            float go = (float)acc[3][0] * sreg[3] + xv[3];
            float cn = sigf(gf) * creg + sigf(gi) * tanhsafe(gG);
            float h = sigf(go) * tanhsafe(cn);
            creg = cn;
            h0bf[((size_t)d * NN + b * 128 + t) * 256 + u] = f2bf(h);
            hbuf[cur ^ 1][u] = (signed char)rintf(h * 127.0f);   // row 0: swizzle mask = 0
        }
        __syncthreads();
    }
}

// ---------------- decoder gate GEMM (MFMA, 128x128 tile, K phases) ----------------
__global__ __launch_bounds__(256) void k_decmm(const u16* __restrict__ Ah, size_t ahStride,
                                               const u16* __restrict__ Axx, size_t axStride,
                                               const u16* __restrict__ Wdec,
                                               const float* __restrict__ bihf, const float* __restrict__ bhhf,
                                               const float* __restrict__ bihb, const float* __restrict__ bhhb,
                                               const float* __restrict__ xp0, int useX,
                                               float* __restrict__ gBuf) {
    __shared__ u16 At[128 * 256];
    __shared__ u16 Bt[128 * 256];
    const int tid = threadIdx.x, lane = tid & 63, wid = tid >> 6;
    const int wm = wid >> 1, wv = wid & 1;
    const int r0 = blockIdx.x * 128, n0 = blockIdx.y * 128, d = blockIdx.z;
    float4v acc[4][4];
    #pragma unroll
    for (int m = 0; m < 4; ++m)
        #pragma unroll
        for (int v = 0; v < 4; ++v) acc[m][v] = (float4v){0.f, 0.f, 0.f, 0.f};
    const int nph = useX ? 2 : 1;
    for (int ph = 0; ph < nph; ++ph) {
        const u16* Asrc = (ph == 0) ? (Ah + (size_t)d * ahStride) : (Axx + (size_t)d * axStride);
        stage128x256(Asrc, n0, 1 << 30, 256, 0, At, tid);
        stage128x256(Wdec + (size_t)d * 1024 * 512, r0, 1 << 30, 512, ph * 256, Bt, tid);
        __syncthreads();
        #pragma unroll
        for (int k = 0; k < 8; ++k) {
            short8v af[4], bf[4];
            #pragma unroll
            for (int m = 0; m < 4; ++m) af[m] = ldfrag(At, wm * 64 + m * 16, k * 32, lane, 512);
            #pragma unroll
            for (int v = 0; v < 4; ++v) bf[v] = ldfrag(Bt, wv * 64 + v * 16, k * 32, lane, 512);
            #pragma unroll
            for (int m = 0; m < 4; ++m)
                #pragma unroll
                for (int v = 0; v < 4; ++v)
                    acc[m][v] = __builtin_amdgcn_mfma_f32_16x16x32_bf16(af[m], bf[v], acc[m][v], 0, 0, 0);
        }
        __syncthreads();
    }
    const float* bih = d ? bihb : bihf;
    const float* bhh = d ? bhhb : bhhf;
    float bs[4]; int rg[4];
    #pragma unroll
    for (int v = 0; v < 4; ++v) {
        rg[v] = r0 + wv * 64 + v * 16 + (lane & 15);
        bs[v] = bih[rg[v]] + bhh[rg[v]];
        if (!useX) bs[v] += xp0[d * 1024 + rg[v]];
    }
    #pragma unroll
    for (int m = 0; m < 4; ++m)
        #pragma unroll
        for (int i = 0; i < 4; ++i) {
            int n = n0 + wm * 64 + m * 16 + ((lane >> 4) << 2) + i;
            #pragma unroll
            for (int v = 0; v < 4; ++v)
                gBuf[((size_t)d * NN + n) * 1024 + rg[v]] = acc[m][v][i] + bs[v];
        }
}

// ---------------- decoder cell ----------------
__global__ __launch_bounds__(256) void k_deccell(const float* __restrict__ gBuf,
                                                 const u16* __restrict__ h0bf,
                                                 float* __restrict__ cDec,
                                                 u16* __restrict__ hsBF, int s) {
    int flat = blockIdx.x * 256 + threadIdx.x;  // 2*2048*256
    int j = flat & 255;
    int n = (flat >> 8) & 2047;
    int d = flat >> 19;
    const float* g = gBuf + ((size_t)d * NN + n) * 1024;
    float gi = g[j], gf = g[j + 256], gg = g[j + 512], go = g[j + 768];
    float cprev = (s == 0) ? bf2f(h0bf[flat]) : cDec[flat];
    float cn = sigf(gf) * cprev + sigf(gi) * tanhsafe(gg);
    float h = sigf(go) * tanhsafe(cn);
    cDec[flat] = cn;
    hsBF[((size_t)(d * 4 + s) * NN + n) * 256 + j] = f2bf(h);
}

// ---------------- projection v7: proj4's LDS pipeline + XCD-bound chunk grid ----------------
// Flat grid 256: chunkI = L&7 (round-robin XCD -> all 32 blocks of a (chunk,d) share an XCD,
// Wp slice L2-resident); idx = L>>3: n0=(idx&15)*128, d=idx>>4. 8 waves (4m x 2v).
// B double-buffered 2x32KB via register prefetch; no-max expsum; 16-slot race-free partials.
__global__ __launch_bounds__(512) void k_proj7(const u16* __restrict__ hsBF,
                                               const u16* __restrict__ WpBF,
                                               const float* __restrict__ bpf, const float* __restrict__ bpb,
                                               const int* __restrict__ winTok,
                                               float* __restrict__ partials,
                                               float* __restrict__ gchar, float* __restrict__ gtag) {
    __shared__ u16 At[128 * 256];        // 64KB, full K, swizzled (rowbytes 512)
    __shared__ u16 Bt[2][64 * 256];      // 2x32KB double buffer, full K, swizzled
    const int tid = threadIdx.x, lane = tid & 63, w = tid >> 6;
    const int wm = w >> 1, wv = w & 1;   // 4 row-groups x 2 col-groups
    const int l15 = lane & 15, hi = lane >> 4;
    const int L = blockIdx.x;
    const int chunkI = L & 7, idx = L >> 3;
    const int n0 = (idx & 15) * 128, d = idx >> 4;
    const int vt0 = chunkI * 16;
    const int nvt = min(16, 125 - vt0);  // 125 x 64 = 8000 v-cols exact
    const float* bp = d ? bpb : bpf;

#define LOADB7(vt_) do {                                                          \
        _Pragma("unroll")                                                         \
        for (int it = 0; it < 4; ++it) {                                          \
            int g = tid + it * 512; int r = g >> 5, kc = (g & 31) << 3;           \
            bregs[it] = *(const short8v*)(WpBF + ((size_t)d * 8000 + (vt_) * 64 + r) * 256 + kc); \
        }                                                                         \
    } while (0)
#define WRITEB7(buf_) do {                                                        \
        _Pragma("unroll")                                                         \
        for (int it = 0; it < 4; ++it) {                                          \
            int g = tid + it * 512; int r = g >> 5, kc = (g & 31) << 3;           \
            int off = (r * 512 + kc * 2) ^ ((r & 7) << 4);                        \
            *(short8v*)((char*)Bt[buf_] + off) = bregs[it];                       \
        }                                                                         \
    } while (0)

    short8v bregs[4];
    for (int s = 0; s < 4; ++s) {
        // stage A(s): 128 rows x 256 k (prev-s readers done: covered by loop-end barriers)
        const u16* hsA = hsBF + (size_t)(d * 4 + s) * NN * 256;
        #pragma unroll
        for (int it = 0; it < 8; ++it) {
            int chunk = tid + it * 512;
            int r = chunk >> 5, kc = (chunk & 31) << 3;
            short8v v8 = *(const short8v*)(hsA + (size_t)(n0 + r) * 256 + kc);
            int off = (r * 512 + kc * 2) ^ ((r & 7) << 4);
            *(short8v*)((char*)At + off) = v8;
        }
        LOADB7(vt0);
        WRITEB7(0);
        // per-row toks for capture
        int tok[2][4];
        #pragma unroll
        for (int m = 0; m < 2; ++m)
            #pragma unroll
            for (int i = 0; i < 4; ++i) {
                int n = n0 + wm * 32 + m * 16 + hi * 4 + i;
                tok[m][i] = (s < 3) ? winTok[(d * 3 + s) * NN + n] : -1;
            }
        float expsum[2][4] = {{0.f, 0.f, 0.f, 0.f}, {0.f, 0.f, 0.f, 0.f}};
        __syncthreads();
        int cur = 0;
        for (int t = 0; t < nvt; ++t) {
            int vt = vt0 + t;
            if (t + 1 < nvt) LOADB7(vt + 1);
            float bpv[2];
            #pragma unroll
            for (int v = 0; v < 2; ++v) bpv[v] = bp[vt * 64 + wv * 32 + v * 16 + l15];
            float4v acc[2][2];
            #pragma unroll
            for (int m = 0; m < 2; ++m)
                #pragma unroll
                for (int v = 0; v < 2; ++v) acc[m][v] = (float4v){0.f, 0.f, 0.f, 0.f};
            #pragma unroll
            for (int kk = 0; kk < 8; ++kk) {
                short8v af[2], bf[2];
                #pragma unroll
                for (int m = 0; m < 2; ++m) af[m] = ldfrag(At, wm * 32 + m * 16, kk * 32, lane, 512);
                #pragma unroll
                for (int v = 0; v < 2; ++v) bf[v] = ldfrag(Bt[cur], wv * 32 + v * 16, kk * 32, lane, 512);
                #pragma unroll
                for (int m = 0; m < 2; ++m)
                    #pragma unroll
                    for (int v = 0; v < 2; ++v)
                        acc[m][v] = __builtin_amdgcn_mfma_f32_16x16x32_bf16(af[m], bf[v], acc[m][v], 0, 0, 0);
            }
            // light epilogue: exp-accumulate + capture (no max: logits bounded)
            #pragma unroll
            for (int m = 0; m < 2; ++m)
                #pragma unroll
                for (int i = 0; i < 4; ++i) {
                    int n = n0 + wm * 32 + m * 16 + hi * 4 + i;
                    float es = 0.0f;
                    #pragma unroll
                    for (int v = 0; v < 2; ++v) {
                        int vgv = vt * 64 + wv * 32 + v * 16 + l15;
                        float lg = acc[m][v][i] + bpv[v];
                        es += __expf(lg);
                        if (vgv == tok[m][i]) gchar[(d * 3 + s) * NN + n] = lg;
                        if (s >= 1 && vgv == 0) gtag[(d * 3 + (s - 1)) * NN + n] = lg;
                    }
                    expsum[m][i] += es;
                }
            __syncthreads();                          // all reads of Bt[cur] done
            if (t + 1 < nvt) WRITEB7(cur ^ 1);
            __syncthreads();                          // writes visible
            cur ^= 1;
        }
        // reduce expsum across the 16 l15 lanes sharing each row; per-(chunk,wv) slot
        #pragma unroll
        for (int m = 0; m < 2; ++m)
            #pragma unroll
            for (int i = 0; i < 4; ++i) {
                float e = expsum[m][i];
                #pragma unroll
                for (int off = 1; off <= 8; off <<= 1) e += __shfl_xor(e, off);
                if (l15 == 0) {
                    int n = n0 + wm * 32 + m * 16 + hi * 4 + i;
                    partials[((size_t)(d * 4 + s) * NN + n) * 16 + chunkI * 2 + wv] = e;
                }
            }
    }
#undef LOADB7
#undef WRITEB7
}

// ---------------- logZ = log(sum of 16 partials) ----------------
__global__ __launch_bounds__(256) void k_lzsum(const float* __restrict__ partials,
                                               float* __restrict__ logZ) {
    int row = blockIdx.x * 256 + threadIdx.x;  // 16384
    const float* p = partials + (size_t)row * 16;
    float s = 0.0f;
    #pragma unroll
    for (int c = 0; c < 16; ++c) s += p[c];
    logZ[row] = __logf(s);
}

// ---------------- P assembly ----------------
__global__ __launch_bounds__(256) void k_passm(const float* __restrict__ gchar,
                                               const float* __restrict__ gtag,
                                               const float* __restrict__ logZ,
                                               float* __restrict__ P) {
    int flat = blockIdx.x * 256 + threadIdx.x;  // 128*3*16
    if (flat >= 128 * 3 * 16) return;
    int b = flat & 15;
    int y = (flat >> 4) % 3;
    int x = flat / 48;
    int nf = b * 128 + min(127, max(0, x - y));
    int nb = b * 128 + 127 - x;
    float pf = 0.0f, pb = 0.0f;
    for (int ss = 0; ss <= y; ++ss) {
        pf += gchar[ss * NN + nf] - logZ[ss * NN + nf];
        pb += gchar[(3 + ss) * NN + nb] - logZ[(4 + ss) * NN + nb];
    }
    pf += gtag[y * NN + nf] - logZ[(y + 1) * NN + nf];
    pb += gtag[(3 + y) * NN + nb] - logZ[(4 + y + 1) * NN + nb];
    P[flat] = 0.5f * (pf + pb);
}

// ---------------- semi-CRF scan + loss: single wave, P in LDS, zero barriers in loop ----------
__global__ __launch_bounds__(64) void k_scan(const float* __restrict__ P, float* __restrict__ out) {
    __shared__ float Pl[128 * 48];
    int tid = threadIdx.x;
    #pragma unroll
    for (int it = 0; it < 96; ++it) Pl[tid + it * 64] = P[tid + it * 64];
    __syncthreads();   // one wave: cheap; ensures LDS visible
    if (tid < 16) {
        int b = tid;
        float b0 = 0.f, b1 = 0.f, b2 = 0.f, tot = 0.f;
        for (int j = 1; j <= 128; ++j) {
            float c0 = b0 + Pl[((j - 1) * 3 + 0) * 16 + b];
            float c1 = (j >= 2) ? b1 + Pl[((j - 1) * 3 + 1) * 16 + b] : -1e30f;
            float c2 = (j >= 3) ? b2 + Pl[((j - 1) * 3 + 2) * 16 + b] : -1e30f;
            float mx = fmaxf(c0, fmaxf(c1, c2));
            float sv = __expf(c0 - mx) + __expf(c1 - mx) + __expf(c2 - mx);
            tot = mx + __logf(sv);
            b2 = b1; b1 = b0; b0 = tot;
        }
        #pragma unroll
        for (int off = 1; off <= 8; off <<= 1) tot += __shfl_xor(tot, off);
        if (b == 0) out[0] = -tot / 16.0f;
    }
}

// ---------------- launch ----------------
extern "C" void kernel_launch(void* const* d_in, const int* in_sizes, int n_in,
                              void* d_out, int out_size, void* d_ws, size_t ws_size,
                              hipStream_t stream) {
    const int* S = (const int*)d_in[0];
    const float* emb = (const float*)d_in[1];
    const float* eWih = (const float*)d_in[2];
    const float* eWhh = (const float*)d_in[3];
    const float* ebih = (const float*)d_in[4];
    const float* ebhh = (const float*)d_in[5];
    const float* fWih = (const float*)d_in[6];
    const float* fWhh = (const float*)d_in[7];
    const float* fbih = (const float*)d_in[8];
    const float* fbhh = (const float*)d_in[9];
    const float* fWp  = (const float*)d_in[10];
    const float* fbp  = (const float*)d_in[11];
    const float* bWih = (const float*)d_in[12];
    const float* bWhh = (const float*)d_in[13];
    const float* bbih = (const float*)d_in[14];
    const float* bbhh = (const float*)d_in[15];
    const float* bWp  = (const float*)d_in[16];
    const float* bbp  = (const float*)d_in[17];

    float* w = (float*)d_ws;
    u16* WpBF    = (u16*)(w + OFF_WPBF);
    u16* WdecBF  = (u16*)(w + OFF_WDEC);
    u16* xEncBF  = (u16*)(w + OFF_XENC);
    u16* h0bf    = (u16*)(w + OFF_H0BF);
    u16* decXBF  = (u16*)(w + OFF_DECX);
    float* cDec  = w + OFF_CDEC;
    u16* hsBF    = (u16*)(w + OFF_HSBF);
    float* gBuf  = w + OFF_GBUF;
    float* xpT   = gBuf;      // aliased: consumed by k_enc5 before decoder writes gBuf
    float* partials = gBuf;   // aliased: used only after decoder
    float* logZ  = w + OFF_LOGZ;
    float* gchar = w + OFF_GCH;
    float* gtag  = w + OFF_GTG;
    float* Pm    = w + OFF_P;
    int* winTok  = (int*)(w + OFF_WTOK);
    float* xp0   = w + OFF_XP0;
    u16* encW    = (u16*)(w + OFF_ENCW);
    float* sEnc  = w + OFF_SENC;
    float* sQ    = w + OFF_SQ;
    signed char* wqEnc = (signed char*)(w + OFF_WQI8);

    k_wpbf<<<2000, 256, 0, stream>>>(fWp, bWp, WpBF);
    k_wdecbf<<<512, 256, 0, stream>>>(fWhh, fWih, bWhh, bWih, WdecBF);
    k_wencbf<<<256, 256, 0, stream>>>(eWhh, eWih, encW);
    k_escale<<<4, 256, 0, stream>>>(eWhh, sEnc, sQ);
    k_wq2<<<64, 256, 0, stream>>>(eWhh, sQ, wqEnc);
    k_xenc<<<512, 256, 0, stream>>>(S, emb, xEncBF);
    k_decx<<<1536, 256, 0, stream>>>(S, emb, decXBF, winTok);
    k_xp0<<<8, 256, 0, stream>>>(emb, fWih, bWih, xp0);

    k_xproj<<<dim3(8, 16, 2), 256, 0, stream>>>(xEncBF, encW, ebih, ebhh, xpT);
    k_enc5<<<32, 1024, 0, stream>>>(wqEnc, sEnc, (const float4v*)xpT, h0bf);

    for (int s = 0; s < 4; ++s) {
        const u16* Ah; size_t ahS;
        const u16* Axx; size_t axS;
        if (s == 0) {
            Ah = h0bf; ahS = (size_t)NN * 256;
            Axx = decXBF; axS = (size_t)3 * NN * 256;  // unused
        } else {
            Ah = hsBF + (size_t)(s - 1) * NN * 256; ahS = (size_t)4 * NN * 256;
            Axx = decXBF + (size_t)(s - 1) * NN * 256; axS = (size_t)3 * NN * 256;
        }
        k_decmm<<<dim3(8, 16, 2), 256, 0, stream>>>(Ah, ahS, Axx, axS, WdecBF,
                                                    fbih, fbhh, bbih, bbhh, xp0,
                                                    (s == 0) ? 0 : 1, gBuf);
        k_deccell<<<4096, 256, 0, stream>>>(gBuf, h0bf, cDec, hsBF, s);
    }

    k_proj7<<<256, 512, 0, stream>>>(hsBF, WpBF, fbp, bbp, winTok,
                                     partials, gchar, gtag);
    k_lzsum<<<64, 256, 0, stream>>>(partials, logZ);
    k_passm<<<24, 256, 0, stream>>>(gchar, gtag, logZ, Pm);
    k_scan<<<1, 64, 0, stream>>>(Pm, (float*)d_out);
}

// Round 16
// 492.578 us; speedup vs baseline: 1.3353x; 1.0439x over previous
//
#include <hip/hip_runtime.h>
#include <math.h>

#define VOCAB 8000
#define NN 2048   /* B*T */

typedef unsigned short u16;
typedef __attribute__((ext_vector_type(8))) short short8v;
typedef __attribute__((ext_vector_type(4))) short short4v;
typedef __attribute__((ext_vector_type(4))) float float4v;
typedef __attribute__((ext_vector_type(4))) int int4v;

// ---- workspace offsets (in float slots) ----
#define OFF_WPBF   0ul          /* bf16 [2][8000][256]      2,048,000 */
#define OFF_WDEC   2048000ul    /* bf16 [2][1024][512]        524,288 */
#define OFF_XENC   2572288ul    /* bf16 [2][128][16][256]     524,288 */
#define OFF_H0BF   4153344ul    /* bf16 [2][2048][256]        524,288 */
#define OFF_DECX   4677632ul    /* bf16 [2][3][2048][256]   1,572,864 */
#define OFF_CDEC   6250496ul    /* f32  [2][2048][256]      1,048,576 */
#define OFF_HSBF   7299072ul    /* bf16 [8][2048][256]      2,097,152 */
#define OFF_GBUF   9396224ul    /* f32  4,194,304 (aliased: xpT, then decoder gBuf, then partials[16384][16]) */
#define OFF_LOGZ   13590528ul   /* f32  [8][2048]              16,384 */
#define OFF_GCH    13606912ul   /* f32  [2][3][2048]           12,288 */
#define OFF_GTG    13619200ul   /* f32  [2][3][2048]           12,288 */
#define OFF_P      13631488ul   /* f32  [128][3][16]            6,144 */
#define OFF_WTOK   13637632ul   /* int  [2][3][2048]           12,288 */
#define OFF_XP0    13649920ul   /* f32  [2][1024]               2,048 */
#define OFF_ENCW   13652032ul   /* bf16 [1024][512]           262,144 */
#define OFF_SENC   13914240ul   /* f32  [1024] dequant scale    1,024 */
#define OFF_SQ     13915264ul   /* f32  [1024] quant scale      1,024 */
#define OFF_WQI8   13916288ul   /* i8   [16384][16]            65,536 f32 slots */

__device__ __forceinline__ float sigf(float x) { return 1.0f / (1.0f + __expf(-x)); }
__device__ __forceinline__ float tanhsafe(float x) {
    x = fminf(15.0f, fmaxf(-15.0f, x));
    float e = __expf(2.0f * x);
    return (e - 1.0f) / (e + 1.0f);
}
__device__ __forceinline__ u16 f2bf(float f) {
    union { float f; unsigned int u; } x; x.f = f;
    return (u16)((x.u + 0x7fffu + ((x.u >> 16) & 1u)) >> 16);
}
__device__ __forceinline__ float bf2f(u16 x) {
    union { unsigned int u; float f; } v; v.u = ((unsigned int)x) << 16;
    return v.f;
}

// MFMA fragment load from a swizzled LDS tile (bf16). Rows of SB bytes; lane l reads
// row (row + (l&15)), 8 contiguous bf16 at k + (l>>4)*8. XOR swizzle (r&7)<<4.
__device__ __forceinline__ short8v ldfrag(const u16* lds, int row, int k, int lane, int SB) {
    int r = row + (lane & 15);
    int off = r * SB + ((k + ((lane >> 4) << 3)) << 1);
    off ^= (r & 7) << 4;
    return *(const short8v*)((const char*)lds + off);
}

// Stage a 128x256 bf16 tile (row-major, rowstride elems) into swizzled LDS (rowbytes 512).
__device__ __forceinline__ void stage128x256(const u16* __restrict__ g, int row0, int rowmax,
                                             int rowstride, int col0, u16* lds, int tid) {
    #pragma unroll
    for (int it = 0; it < 16; ++it) {
        int chunk = tid + it * 256;
        int r = chunk >> 5;
        int kc = (chunk & 31) << 3;
        short8v v = {0, 0, 0, 0, 0, 0, 0, 0};
        if (row0 + r < rowmax)
            v = *(const short8v*)(g + (size_t)(row0 + r) * rowstride + col0 + kc);
        int off = (r * 512 + kc * 2) ^ ((r & 7) << 4);
        *(short8v*)((char*)lds + off) = v;
    }
}

// ---------------- setup kernels ----------------

__global__ __launch_bounds__(256) void k_wpbf(const float* __restrict__ Wf,
                                              const float* __restrict__ Wb,
                                              u16* __restrict__ out) {
    int chunk = blockIdx.x * 256 + threadIdx.x;   // 2*8000*32 = 512000
    int kc = (chunk & 31) << 3;
    int v = (chunk >> 5) % 8000;
    int d = chunk / (8000 * 32);
    const float* src = (d ? Wb : Wf) + (size_t)v * 256 + kc;
    u16 t8[8];
    #pragma unroll
    for (int j = 0; j < 8; ++j) t8[j] = f2bf(src[j]);
    *(short8v*)(out + ((size_t)d * 8000 + v) * 256 + kc) = *(short8v*)t8;
}

// WdecBF[d][r][k]: k<256 -> Whh[r][k], else Wih[r][k-256]
__global__ __launch_bounds__(256) void k_wdecbf(const float* __restrict__ fWhh, const float* __restrict__ fWih,
                                                const float* __restrict__ bWhh, const float* __restrict__ bWih,
                                                u16* __restrict__ out) {
    int chunk = blockIdx.x * 256 + threadIdx.x;   // 2*1024*64 = 131072
    int kc = (chunk & 63) << 3;
    int r = (chunk >> 6) & 1023;
    int d = chunk >> 16;
    const float* Whh = d ? bWhh : fWhh;
    const float* Wih = d ? bWih : fWih;
    const float* src = (kc < 256) ? (Whh + (size_t)r * 256 + kc) : (Wih + (size_t)r * 256 + (kc - 256));
    u16 t8[8];
    #pragma unroll
    for (int j = 0; j < 8; ++j) t8[j] = f2bf(src[j]);
    *(short8v*)(out + ((size_t)d * 1024 + r) * 512 + kc) = *(short8v*)t8;
}

// encW[r][k]: k<256 -> enc_Whh[r][k], else enc_Wih[r][k-256]  (Wih half used by k_xproj)
__global__ __launch_bounds__(256) void k_wencbf(const float* __restrict__ Whh, const float* __restrict__ Wih,
                                                u16* __restrict__ out) {
    int chunk = blockIdx.x * 256 + threadIdx.x;   // 1024*64 = 65536
    int kc = (chunk & 63) << 3;
    int r = chunk >> 6;
    const float* src = (kc < 256) ? (Whh + (size_t)r * 256 + kc) : (Wih + (size_t)r * 256 + (kc - 256));
    u16 t8[8];
    #pragma unroll
    for (int j = 0; j < 8; ++j) t8[j] = f2bf(src[j]);
    *(short8v*)(out + (size_t)r * 512 + kc) = *(short8v*)t8;
}

// per-row scales for enc Whh int8 quantization
__global__ __launch_bounds__(256) void k_escale(const float* __restrict__ Whh,
                                                float* __restrict__ s_enc,
                                                float* __restrict__ sq) {
    int r = blockIdx.x * 256 + threadIdx.x;
    if (r >= 1024) return;
    float m = 0.0f;
    for (int k = 0; k < 256; ++k) m = fmaxf(m, fabsf(Whh[r * 256 + k]));
    s_enc[r] = m / 16129.0f;            // m/(127*127): dequant (folds h scale 1/127)
    sq[r] = (m > 0.0f) ? 127.0f / m : 0.0f;
}

// wq for k_enc5: lin = (((w*4+c)*4+ks)*64+lane) ->
// gate-row r = c*256 + w*16 + (lane&15), k = ks*64 + (lane>>4)*16 .. +16
__global__ __launch_bounds__(256) void k_wq2(const float* __restrict__ Whh,
                                             const float* __restrict__ sq,
                                             signed char* __restrict__ wq) {
    int lin = blockIdx.x * 256 + threadIdx.x;   // 16*4*4*64 = 16384
    int lane = lin & 63;
    int ks = (lin >> 6) & 3;
    int c = (lin >> 8) & 3;
    int w = lin >> 10;
    int r = c * 256 + w * 16 + (lane & 15);
    int kb = ks * 64 + ((lane >> 4) << 4);
    float s = sq[r];
    signed char o16[16];
    #pragma unroll
    for (int j = 0; j < 16; ++j) {
        float q = rintf(Whh[r * 256 + kb + j] * s);
        q = fminf(127.0f, fmaxf(-127.0f, q));
        o16[j] = (signed char)q;
    }
    *(int4v*)(wq + (size_t)lin * 16) = *(int4v*)o16;
}

// xEncBF[d][t][b][k] = bf16(emb[tok]), tok = t==0 ? 0 : (fwd S[b][t-1] / bwd S[b][128-t])
__global__ __launch_bounds__(256) void k_xenc(const int* __restrict__ S, const float* __restrict__ emb,
                                              u16* __restrict__ out) {
    int chunk = blockIdx.x * 256 + threadIdx.x;   // 2*128*16*32 = 131072
    int kc = (chunk & 31) << 3;
    int b = (chunk >> 5) & 15;
    int t = (chunk >> 9) & 127;
    int d = chunk >> 16;
    int tok = 0;
    if (t > 0) tok = d ? S[b * 128 + 128 - t] : S[b * 128 + t - 1];
    const float* src = emb + (size_t)tok * 256 + kc;
    u16 t8[8];
    #pragma unroll
    for (int j = 0; j < 8; ++j) t8[j] = f2bf(src[j]);
    *(short8v*)(out + (size_t)(((d * 128 + t) * 16) + b) * 256 + kc) = *(short8v*)t8;
}

__global__ __launch_bounds__(256) void k_decx(const int* __restrict__ S, const float* __restrict__ emb,
                                              u16* __restrict__ decX, int* __restrict__ winTok) {
    int chunk = blockIdx.x * 256 + threadIdx.x;   // 2*3*2048*32 = 393216
    int kc = (chunk & 31) << 3;
    int n = (chunk >> 5) & 2047;
    int r2 = chunk >> 16;
    int s = r2 % 3, d = r2 / 3;
    int b = n >> 7, tq = n & 127;
    int pos = min(tq + s, 127);
    int tok = d ? S[b * 128 + 127 - pos] : S[b * 128 + pos];
    const float* src = emb + (size_t)tok * 256 + kc;
    u16 t8[8];
    #pragma unroll
    for (int j = 0; j < 8; ++j) t8[j] = f2bf(src[j]);
    *(short8v*)(decX + ((size_t)(d * 3 + s) * NN + n) * 256 + kc) = *(short8v*)t8;
    if ((chunk & 31) == 0) winTok[(d * 3 + s) * NN + n] = tok;
}

// xp0[d][r] = emb[PART=0] . dec_Wih_d[r]  (f32, exact)
__global__ __launch_bounds__(256) void k_xp0(const float* __restrict__ emb,
                                             const float* __restrict__ Wihf,
                                             const float* __restrict__ Wihb,
                                             float* __restrict__ xp0) {
    int idx = blockIdx.x * 256 + threadIdx.x;  // 2048
    int d = idx >> 10, r = idx & 1023;
    const float* Wih = d ? Wihb : Wihf;
    float acc = 0.0f;
    for (int k = 0; k < 256; ++k) acc = fmaf(emb[k], Wih[r * 256 + k], acc);
    xp0[idx] = acc;
}

// ---------------- encoder x-projection GEMM -> k_enc5 layout ----------------
__global__ __launch_bounds__(256) void k_xproj(const u16* __restrict__ xEncBF,
                                               const u16* __restrict__ encW,
                                               const float* __restrict__ ebih,
                                               const float* __restrict__ ebhh,
                                               float* __restrict__ xpT) {
    __shared__ u16 At[128 * 256];
    __shared__ u16 Bt[128 * 256];
    const int tid = threadIdx.x, lane = tid & 63, wid = tid >> 6;
    const int wm = wid >> 1, wv = wid & 1;
    const int r0 = blockIdx.x * 128, n0 = blockIdx.y * 128, d = blockIdx.z;
    stage128x256(xEncBF + (size_t)d * 2048 * 256, n0, 1 << 30, 256, 0, At, tid);
    stage128x256(encW, r0, 1 << 30, 512, 256, Bt, tid);
    __syncthreads();
    float4v acc[4][4];
    #pragma unroll
    for (int m = 0; m < 4; ++m)
        #pragma unroll
        for (int v = 0; v < 4; ++v) acc[m][v] = (float4v){0.f, 0.f, 0.f, 0.f};
    #pragma unroll
    for (int k = 0; k < 8; ++k) {
        short8v af[4], bf[4];
        #pragma unroll
        for (int m = 0; m < 4; ++m) af[m] = ldfrag(At, wm * 64 + m * 16, k * 32, lane, 512);
        #pragma unroll
        for (int v = 0; v < 4; ++v) bf[v] = ldfrag(Bt, wv * 64 + v * 16, k * 32, lane, 512);
        #pragma unroll
        for (int m = 0; m < 4; ++m)
            #pragma unroll
            for (int v = 0; v < 4; ++v)
                acc[m][v] = __builtin_amdgcn_mfma_f32_16x16x32_bf16(af[m], bf[v], acc[m][v], 0, 0, 0);
    }
    float bs[4]; int rg[4];
    #pragma unroll
    for (int v = 0; v < 4; ++v) {
        rg[v] = r0 + wv * 64 + v * 16 + (lane & 15);
        bs[v] = ebih[rg[v]] + ebhh[rg[v]];
    }
    #pragma unroll
    for (int m = 0; m < 4; ++m)
        #pragma unroll
        for (int i = 0; i < 4; ++i) {
            int n = n0 + wm * 64 + m * 16 + ((lane >> 4) << 2) + i;
            int t_ = n >> 4, bfull = n & 15;
            #pragma unroll
            for (int v = 0; v < 4; ++v) {
                int g = rg[v] >> 8, u = rg[v] & 255;
                size_t idx4 = (((size_t)(d * 16 + bfull) * 128 + t_) * 16 + (u >> 4)) * 16 + (u & 15);
                xpT[idx4 * 4 + g] = acc[m][v][i] + bs[v];
            }
        }
}

// ---------------- encoder: 1 batch/block (32 blocks), swizzled hbuf, pipelined xv ----------
__global__ __launch_bounds__(1024) void k_enc5(const signed char* __restrict__ wq,
                                               const float* __restrict__ s_enc,
                                               const float4v* __restrict__ xpT4,
                                               u16* __restrict__ h0bf) {
    __shared__ signed char hbuf[2][4096];    // [16 rows][256 u] int8, XOR-swizzled; row 0 live
    const int tid = threadIdx.x, lane = tid & 63, w = tid >> 6;   // w in [0,16)
    const int blk = blockIdx.x, d = blk >> 4, b = blk & 15;
    const int l15 = lane & 15, hi = lane >> 4;
    int4v breg[4][4];
    #pragma unroll
    for (int c = 0; c < 4; ++c)
        #pragma unroll
        for (int ks = 0; ks < 4; ++ks)
            breg[c][ks] = *(const int4v*)(wq + ((size_t)(((w * 4 + c) * 4 + ks) * 64 + lane)) * 16);
    float sreg[4];
    #pragma unroll
    for (int c = 0; c < 4; ++c) sreg[c] = s_enc[c * 256 + w * 16 + l15];
    float creg = 0.0f;
    ((long*)hbuf)[tid] = 0l;
    const bool cellane = (lane < 16);
    const int u = w * 16 + l15;
    const float4v* xbase = xpT4 + ((size_t)(d * 16 + b) * 128) * 256 + w * 16 + l15;
    float4v xv_next = {0.f, 0.f, 0.f, 0.f};
    if (cellane) xv_next = xbase[0];
    __syncthreads();
    for (int t = 0; t < 128; ++t) {
        int cur = t & 1;
        float4v xv = xv_next;
        if (cellane && t < 127) xv_next = xbase[(size_t)(t + 1) * 256];
        int4v af[4];
        #pragma unroll
        for (int ks = 0; ks < 4; ++ks) {
            int off = (l15 * 256 + ks * 64 + hi * 16) ^ ((l15 & 7) << 4);
            af[ks] = *(const int4v*)(hbuf[cur] + off);
        }
        int4v acc[4];
        #pragma unroll
        for (int c = 0; c < 4; ++c) {
            acc[c] = (int4v){0, 0, 0, 0};
            #pragma unroll
            for (int ks = 0; ks < 4; ++ks)
                acc[c] = __builtin_amdgcn_mfma_i32_16x16x64_i8(af[ks], breg[c][ks], acc[c], 0, 0, 0);
        }
        if (cellane) {
            float gi = (float)acc[0][0] * sreg[0] + xv[0];
            float gf = (float)acc[1][0] * sreg[1] + xv[1];
            float gG = (float)acc[2][0] * sreg[2] + xv[2];
            float go = (float)acc[3][0] * sreg[3] + xv[3];
            float cn = sigf(gf) * creg + sigf(gi) * tanhsafe(gG);
            float h = sigf(go) * tanhsafe(cn);
            creg = cn;
            h0bf[((size_t)d * NN + b * 128 + t) * 256 + u] = f2bf(h);
            hbuf[cur ^ 1][u] = (signed char)rintf(h * 127.0f);   // row 0: swizzle mask = 0
        }
        __syncthreads();
    }
}

// ---------------- decoder gate GEMM (MFMA, 128x128 tile, K phases) ----------------
__global__ __launch_bounds__(256) void k_decmm(const u16* __restrict__ Ah, size_t ahStride,
                                               const u16* __restrict__ Axx, size_t axStride,
                                               const u16* __restrict__ Wdec,
                                               const float* __restrict__ bihf, const float* __restrict__ bhhf,
                                               const float* __restrict__ bihb, const float* __restrict__ bhhb,
                                               const float* __restrict__ xp0, int useX,
                                               float* __restrict__ gBuf) {
    __shared__ u16 At[128 * 256];
    __shared__ u16 Bt[128 * 256];
    const int tid = threadIdx.x, lane = tid & 63, wid = tid >> 6;
    const int wm = wid >> 1, wv = wid & 1;
    const int r0 = blockIdx.x * 128, n0 = blockIdx.y * 128, d = blockIdx.z;
    float4v acc[4][4];
    #pragma unroll
    for (int m = 0; m < 4; ++m)
        #pragma unroll
        for (int v = 0; v < 4; ++v) acc[m][v] = (float4v){0.f, 0.f, 0.f, 0.f};
    const int nph = useX ? 2 : 1;
    for (int ph = 0; ph < nph; ++ph) {
        const u16* Asrc = (ph == 0) ? (Ah + (size_t)d * ahStride) : (Axx + (size_t)d * axStride);
        stage128x256(Asrc, n0, 1 << 30, 256, 0, At, tid);
        stage128x256(Wdec + (size_t)d * 1024 * 512, r0, 1 << 30, 512, ph * 256, Bt, tid);
        __syncthreads();
        #pragma unroll
        for (int k = 0; k < 8; ++k) {
            short8v af[4], bf[4];
            #pragma unroll
            for (int m = 0; m < 4; ++m) af[m] = ldfrag(At, wm * 64 + m * 16, k * 32, lane, 512);
            #pragma unroll
            for (int v = 0; v < 4; ++v) bf[v] = ldfrag(Bt, wv * 64 + v * 16, k * 32, lane, 512);
            #pragma unroll
            for (int m = 0; m < 4; ++m)
                #pragma unroll
                for (int v = 0; v < 4; ++v)
                    acc[m][v] = __builtin_amdgcn_mfma_f32_16x16x32_bf16(af[m], bf[v], acc[m][v], 0, 0, 0);
        }
        __syncthreads();
    }
    const float* bih = d ? bihb : bihf;
    const float* bhh = d ? bhhb : bhhf;
    float bs[4]; int rg[4];
    #pragma unroll
    for (int v = 0; v < 4; ++v) {
        rg[v] = r0 + wv * 64 + v * 16 + (lane & 15);
        bs[v] = bih[rg[v]] + bhh[rg[v]];
        if (!useX) bs[v] += xp0[d * 1024 + rg[v]];
    }
    #pragma unroll
    for (int m = 0; m < 4; ++m)
        #pragma unroll
        for (int i = 0; i < 4; ++i) {
            int n = n0 + wm * 64 + m * 16 + ((lane >> 4) << 2) + i;
            #pragma unroll
            for (int v = 0; v < 4; ++v)
                gBuf[((size_t)d * NN + n) * 1024 + rg[v]] = acc[m][v][i] + bs[v];
        }
}

// ---------------- decoder cell ----------------
__global__ __launch_bounds__(256) void k_deccell(const float* __restrict__ gBuf,
                                                 const u16* __restrict__ h0bf,
                                                 float* __restrict__ cDec,
                                                 u16* __restrict__ hsBF, int s) {
    int flat = blockIdx.x * 256 + threadIdx.x;  // 2*2048*256
    int j = flat & 255;
    int n = (flat >> 8) & 2047;
    int d = flat >> 19;
    const float* g = gBuf + ((size_t)d * NN + n) * 1024;
    float gi = g[j], gf = g[j + 256], gg = g[j + 512], go = g[j + 768];
    float cprev = (s == 0) ? bf2f(h0bf[flat]) : cDec[flat];
    float cn = sigf(gf) * cprev + sigf(gi) * tanhsafe(gg);
    float h = sigf(go) * tanhsafe(cn);
    cDec[flat] = cn;
    hsBF[((size_t)(d * 4 + s) * NN + n) * 256 + j] = f2bf(h);
}

// ---------------- projection v8: proj7 + A-fragments hoisted to registers ----------------
// A frags depend only on (m,kk): load once per s (64 VGPR), reuse across all 16 vt.
// Halves per-iter LDS reads (256 -> 128 per CU) -- the binding resource per round-15 PMC.
__global__ __launch_bounds__(512, 2) void k_proj8(const u16* __restrict__ hsBF,
                                                  const u16* __restrict__ WpBF,
                                                  const float* __restrict__ bpf, const float* __restrict__ bpb,
                                                  const int* __restrict__ winTok,
                                                  float* __restrict__ partials,
                                                  float* __restrict__ gchar, float* __restrict__ gtag) {
    __shared__ u16 At[128 * 256];        // 64KB, full K, swizzled (rowbytes 512)
    __shared__ u16 Bt[2][64 * 256];      // 2x32KB double buffer, full K, swizzled
    const int tid = threadIdx.x, lane = tid & 63, w = tid >> 6;
    const int wm = w >> 1, wv = w & 1;   // 4 row-groups x 2 col-groups
    const int l15 = lane & 15, hi = lane >> 4;
    const int L = blockIdx.x;
    const int chunkI = L & 7, idx = L >> 3;
    const int n0 = (idx & 15) * 128, d = idx >> 4;
    const int vt0 = chunkI * 16;
    const int nvt = min(16, 125 - vt0);  // 125 x 64 = 8000 v-cols exact
    const float* bp = d ? bpb : bpf;

#define LOADB8(vt_) do {                                                          \
        _Pragma("unroll")                                                         \
        for (int it = 0; it < 4; ++it) {                                          \
            int g = tid + it * 512; int r = g >> 5, kc = (g & 31) << 3;           \
            bregs[it] = *(const short8v*)(WpBF + ((size_t)d * 8000 + (vt_) * 64 + r) * 256 + kc); \
        }                                                                         \
    } while (0)
#define WRITEB8(buf_) do {                                                        \
        _Pragma("unroll")                                                         \
        for (int it = 0; it < 4; ++it) {                                          \
            int g = tid + it * 512; int r = g >> 5, kc = (g & 31) << 3;           \
            int off = (r * 512 + kc * 2) ^ ((r & 7) << 4);                        \
            *(short8v*)((char*)Bt[buf_] + off) = bregs[it];                       \
        }                                                                         \
    } while (0)

    short8v bregs[4];
    for (int s = 0; s < 4; ++s) {
        // stage A(s): 128 rows x 256 k (prev-s readers done: covered by loop-end barriers)
        const u16* hsA = hsBF + (size_t)(d * 4 + s) * NN * 256;
        #pragma unroll
        for (int it = 0; it < 8; ++it) {
            int chunk = tid + it * 512;
            int r = chunk >> 5, kc = (chunk & 31) << 3;
            short8v v8 = *(const short8v*)(hsA + (size_t)(n0 + r) * 256 + kc);
            int off = (r * 512 + kc * 2) ^ ((r & 7) << 4);
            *(short8v*)((char*)At + off) = v8;
        }
        LOADB8(vt0);
        WRITEB8(0);
        // per-row toks for capture
        int tok[2][4];
        #pragma unroll
        for (int m = 0; m < 2; ++m)
            #pragma unroll
            for (int i = 0; i < 4; ++i) {
                int n = n0 + wm * 32 + m * 16 + hi * 4 + i;
                tok[m][i] = (s < 3) ? winTok[(d * 3 + s) * NN + n] : -1;
            }
        float expsum[2][4] = {{0.f, 0.f, 0.f, 0.f}, {0.f, 0.f, 0.f, 0.f}};
        __syncthreads();                 // At + Bt[0] visible
        // hoist A fragments: (m,kk) only -> 16 frags = 64 VGPR, reused for all vt
        short8v afr[2][8];
        #pragma unroll
        for (int m = 0; m < 2; ++m)
            #pragma unroll
            for (int kk = 0; kk < 8; ++kk) {
                afr[m][kk] = ldfrag(At, wm * 32 + m * 16, kk * 32, lane, 512);
                asm volatile("" : "+v"(afr[m][kk]));   // pin: not rematerializable
            }
        int cur = 0;
        for (int t = 0; t < nvt; ++t) {
            int vt = vt0 + t;
            if (t + 1 < nvt) LOADB8(vt + 1);
            float bpv[2];
            #pragma unroll
            for (int v = 0; v < 2; ++v) bpv[v] = bp[vt * 64 + wv * 32 + v * 16 + l15];
            float4v acc[2][2];
            #pragma unroll
            for (int m = 0; m < 2; ++m)
                #pragma unroll
                for (int v = 0; v < 2; ++v) acc[m][v] = (float4v){0.f, 0.f, 0.f, 0.f};
            #pragma unroll
            for (int kk = 0; kk < 8; ++kk) {
                short8v bf[2];
                #pragma unroll
                for (int v = 0; v < 2; ++v) bf[v] = ldfrag(Bt[cur], wv * 32 + v * 16, kk * 32, lane, 512);
                #pragma unroll
                for (int m = 0; m < 2; ++m)
                    #pragma unroll
                    for (int v = 0; v < 2; ++v)
                        acc[m][v] = __builtin_amdgcn_mfma_f32_16x16x32_bf16(afr[m][kk], bf[v], acc[m][v], 0, 0, 0);
            }
            // light epilogue: exp-accumulate + capture (no max: logits bounded)
            #pragma unroll
            for (int m = 0; m < 2; ++m)
                #pragma unroll
                for (int i = 0; i < 4; ++i) {
                    int n = n0 + wm * 32 + m * 16 + hi * 4 + i;
                    float es = 0.0f;
                    #pragma unroll
                    for (int v = 0; v < 2; ++v) {
                        int vgv = vt * 64 + wv * 32 + v * 16 + l15;
                        float lg = acc[m][v][i] + bpv[v];
                        es += __expf(lg);
                        if (vgv == tok[m][i]) gchar[(d * 3 + s) * NN + n] = lg;
                        if (s >= 1 && vgv == 0) gtag[(d * 3 + (s - 1)) * NN + n] = lg;
                    }
                    expsum[m][i] += es;
                }
            __syncthreads();                          // all reads of Bt[cur] done
            if (t + 1 < nvt) WRITEB8(cur ^ 1);
            __syncthreads();                          // writes visible
            cur ^= 1;
        }
        // reduce expsum across the 16 l15 lanes sharing each row; per-(chunk,wv) slot
        #pragma unroll
        for (int m = 0; m < 2; ++m)
            #pragma unroll
            for (int i = 0; i < 4; ++i) {
                float e = expsum[m][i];
                #pragma unroll
                for (int off = 1; off <= 8; off <<= 1) e += __shfl_xor(e, off);
                if (l15 == 0) {
                    int n = n0 + wm * 32 + m * 16 + hi * 4 + i;
                    partials[((size_t)(d * 4 + s) * NN + n) * 16 + chunkI * 2 + wv] = e;
                }
            }
    }
#undef LOADB8
#undef WRITEB8
}

// ---------------- logZ = log(sum of 16 partials) ----------------
__global__ __launch_bounds__(256) void k_lzsum(const float* __restrict__ partials,
                                               float* __restrict__ logZ) {
    int row = blockIdx.x * 256 + threadIdx.x;  // 16384
    const float* p = partials + (size_t)row * 16;
    float s = 0.0f;
    #pragma unroll
    for (int c = 0; c < 16; ++c) s += p[c];
    logZ[row] = __logf(s);
}

// ---------------- P assembly ----------------
__global__ __launch_bounds__(256) void k_passm(const float* __restrict__ gchar,
                                               const float* __restrict__ gtag,
                                               const float* __restrict__ logZ,
                                               float* __restrict__ P) {
    int flat = blockIdx.x * 256 + threadIdx.x;  // 128*3*16
    if (flat >= 128 * 3 * 16) return;
    int b = flat & 15;
    int y = (flat >> 4) % 3;
    int x = flat / 48;
    int nf = b * 128 + min(127, max(0, x - y));
    int nb = b * 128 + 127 - x;
    float pf = 0.0f, pb = 0.0f;
    for (int ss = 0; ss <= y; ++ss) {
        pf += gchar[ss * NN + nf] - logZ[ss * NN + nf];
        pb += gchar[(3 + ss) * NN + nb] - logZ[(4 + ss) * NN + nb];
    }
    pf += gtag[y * NN + nf] - logZ[(y + 1) * NN + nf];
    pb += gtag[(3 + y) * NN + nb] - logZ[(4 + y + 1) * NN + nb];
    P[flat] = 0.5f * (pf + pb);
}

// ---------------- semi-CRF scan + loss: single wave, P in LDS, zero barriers in loop ----------
__global__ __launch_bounds__(64) void k_scan(const float* __restrict__ P, float* __restrict__ out) {
    __shared__ float Pl[128 * 48];
    int tid = threadIdx.x;
    #pragma unroll
    for (int it = 0; it < 96; ++it) Pl[tid + it * 64] = P[tid + it * 64];
    __syncthreads();   // one wave: cheap; ensures LDS visible
    if (tid < 16) {
        int b = tid;
        float b0 = 0.f, b1 = 0.f, b2 = 0.f, tot = 0.f;
        for (int j = 1; j <= 128; ++j) {
            float c0 = b0 + Pl[((j - 1) * 3 + 0) * 16 + b];
            float c1 = (j >= 2) ? b1 + Pl[((j - 1) * 3 + 1) * 16 + b] : -1e30f;
            float c2 = (j >= 3) ? b2 + Pl[((j - 1) * 3 + 2) * 16 + b] : -1e30f;
            float mx = fmaxf(c0, fmaxf(c1, c2));
            float sv = __expf(c0 - mx) + __expf(c1 - mx) + __expf(c2 - mx);
            tot = mx + __logf(sv);
            b2 = b1; b1 = b0; b0 = tot;
        }
        #pragma unroll
        for (int off = 1; off <= 8; off <<= 1) tot += __shfl_xor(tot, off);
        if (b == 0) out[0] = -tot / 16.0f;
    }
}

// ---------------- launch ----------------
extern "C" void kernel_launch(void* const* d_in, const int* in_sizes, int n_in,
                              void* d_out, int out_size, void* d_ws, size_t ws_size,
                              hipStream_t stream) {
    const int* S = (const int*)d_in[0];
    const float* emb = (const float*)d_in[1];
    const float* eWih = (const float*)d_in[2];
    const float* eWhh = (const float*)d_in[3];
    const float* ebih = (const float*)d_in[4];
    const float* ebhh = (const float*)d_in[5];
    const float* fWih = (const float*)d_in[6];
    const float* fWhh = (const float*)d_in[7];
    const float* fbih = (const float*)d_in[8];
    const float* fbhh = (const float*)d_in[9];
    const float* fWp  = (const float*)d_in[10];
    const float* fbp  = (const float*)d_in[11];
    const float* bWih = (const float*)d_in[12];
    const float* bWhh = (const float*)d_in[13];
    const float* bbih = (const float*)d_in[14];
    const float* bbhh = (const float*)d_in[15];
    const float* bWp  = (const float*)d_in[16];
    const float* bbp  = (const float*)d_in[17];

    float* w = (float*)d_ws;
    u16* WpBF    = (u16*)(w + OFF_WPBF);
    u16* WdecBF  = (u16*)(w + OFF_WDEC);
    u16* xEncBF  = (u16*)(w + OFF_XENC);
    u16* h0bf    = (u16*)(w + OFF_H0BF);
    u16* decXBF  = (u16*)(w + OFF_DECX);
    float* cDec  = w + OFF_CDEC;
    u16* hsBF    = (u16*)(w + OFF_HSBF);
    float* gBuf  = w + OFF_GBUF;
    float* xpT   = gBuf;      // aliased: consumed by k_enc5 before decoder writes gBuf
    float* partials = gBuf;   // aliased: used only after decoder
    float* logZ  = w + OFF_LOGZ;
    float* gchar = w + OFF_GCH;
    float* gtag  = w + OFF_GTG;
    float* Pm    = w + OFF_P;
    int* winTok  = (int*)(w + OFF_WTOK);
    float* xp0   = w + OFF_XP0;
    u16* encW    = (u16*)(w + OFF_ENCW);
    float* sEnc  = w + OFF_SENC;
    float* sQ    = w + OFF_SQ;
    signed char* wqEnc = (signed char*)(w + OFF_WQI8);

    k_wpbf<<<2000, 256, 0, stream>>>(fWp, bWp, WpBF);
    k_wdecbf<<<512, 256, 0, stream>>>(fWhh, fWih, bWhh, bWih, WdecBF);
    k_wencbf<<<256, 256, 0, stream>>>(eWhh, eWih, encW);
    k_escale<<<4, 256, 0, stream>>>(eWhh, sEnc, sQ);
    k_wq2<<<64, 256, 0, stream>>>(eWhh, sQ, wqEnc);
    k_xenc<<<512, 256, 0, stream>>>(S, emb, xEncBF);
    k_decx<<<1536, 256, 0, stream>>>(S, emb, decXBF, winTok);
    k_xp0<<<8, 256, 0, stream>>>(emb, fWih, bWih, xp0);

    k_xproj<<<dim3(8, 16, 2), 256, 0, stream>>>(xEncBF, encW, ebih, ebhh, xpT);
    k_enc5<<<32, 1024, 0, stream>>>(wqEnc, sEnc, (const float4v*)xpT, h0bf);

    for (int s = 0; s < 4; ++s) {
        const u16* Ah; size_t ahS;
        const u16* Axx; size_t axS;
        if (s == 0) {
            Ah = h0bf; ahS = (size_t)NN * 256;
            Axx = decXBF; axS = (size_t)3 * NN * 256;  // unused
        } else {
            Ah = hsBF + (size_t)(s - 1) * NN * 256; ahS = (size_t)4 * NN * 256;
            Axx = decXBF + (size_t)(s - 1) * NN * 256; axS = (size_t)3 * NN * 256;
        }
        k_decmm<<<dim3(8, 16, 2), 256, 0, stream>>>(Ah, ahS, Axx, axS, WdecBF,
                                                    fbih, fbhh, bbih, bbhh, xp0,
                                                    (s == 0) ? 0 : 1, gBuf);
        k_deccell<<<4096, 256, 0, stream>>>(gBuf, h0bf, cDec, hsBF, s);
    }

    k_proj8<<<256, 512, 0, stream>>>(hsBF, WpBF, fbp, bbp, winTok,
                                     partials, gchar, gtag);
    k_lzsum<<<64, 256, 0, stream>>>(partials, logZ);
    k_passm<<<24, 256, 0, stream>>>(gchar, gtag, logZ, Pm);
    k_scan<<<1, 64, 0, stream>>>(Pm, (float*)d_out);
}

// Round 17
// 473.287 us; speedup vs baseline: 1.3897x; 1.0408x over previous
//
#include <hip/hip_runtime.h>
#include <math.h>

#define VOCAB 8000
#define NN 2048   /* B*T */

typedef unsigned short u16;
typedef __attribute__((ext_vector_type(8))) short short8v;
typedef __attribute__((ext_vector_type(4))) short short4v;
typedef __attribute__((ext_vector_type(4))) float float4v;
typedef __attribute__((ext_vector_type(4))) int int4v;

// ---- workspace offsets (in float slots) ----
#define OFF_WPBF   0ul          /* bf16 [2][8000][256]      2,048,000 */
#define OFF_WDEC   2048000ul    /* bf16 [2][1024][512]        524,288 */
#define OFF_XENC   2572288ul    /* bf16 [2][128][16][256]     524,288 */
#define OFF_H0BF   4153344ul    /* bf16 [2][2048][256]        524,288 */
#define OFF_DECX   4677632ul    /* bf16 [2][3][2048][256]   1,572,864 */
#define OFF_CDEC   6250496ul    /* f32  [2][2048][256]      1,048,576 */
#define OFF_HSBF   7299072ul    /* bf16 [8][2048][256]      2,097,152 */
#define OFF_GBUF   9396224ul    /* f32  4,194,304 (aliased: xpT, then decoder gBuf, then partials[16384][16]) */
#define OFF_LOGZ   13590528ul   /* f32  [8][2048]              16,384 */
#define OFF_GCH    13606912ul   /* f32  [2][3][2048]           12,288 */
#define OFF_GTG    13619200ul   /* f32  [2][3][2048]           12,288 */
#define OFF_P      13631488ul   /* f32  [128][3][16]            6,144 */
#define OFF_WTOK   13637632ul   /* int  [2][3][2048]           12,288 */
#define OFF_XP0    13649920ul   /* f32  [2][1024]               2,048 */
#define OFF_ENCW   13652032ul   /* bf16 [1024][512]           262,144 */
#define OFF_SENC   13914240ul   /* f32  [1024] dequant scale    1,024 */
#define OFF_SQ     13915264ul   /* f32  [1024] quant scale      1,024 */
#define OFF_WQI8   13916288ul   /* i8   [16384][16]            65,536 f32 slots */
#define OFF_GXD    13981824ul   /* bf16 [2][3][2048][1024]  6,291,456 f32 slots (optional) */
#define WS_NEED_OV ((OFF_GXD + 6291456ul) * 4ul)

__device__ __forceinline__ float sigf(float x) { return 1.0f / (1.0f + __expf(-x)); }
__device__ __forceinline__ float tanhsafe(float x) {
    x = fminf(15.0f, fmaxf(-15.0f, x));
    float e = __expf(2.0f * x);
    return (e - 1.0f) / (e + 1.0f);
}
__device__ __forceinline__ u16 f2bf(float f) {
    union { float f; unsigned int u; } x; x.f = f;
    return (u16)((x.u + 0x7fffu + ((x.u >> 16) & 1u)) >> 16);
}
__device__ __forceinline__ float bf2f(u16 x) {
    union { unsigned int u; float f; } v; v.u = ((unsigned int)x) << 16;
    return v.f;
}

// MFMA fragment load from a swizzled LDS tile (bf16). Rows of SB bytes; lane l reads
// row (row + (l&15)), 8 contiguous bf16 at k + (l>>4)*8. XOR swizzle (r&7)<<4.
__device__ __forceinline__ short8v ldfrag(const u16* lds, int row, int k, int lane, int SB) {
    int r = row + (lane & 15);
    int off = r * SB + ((k + ((lane >> 4) << 3)) << 1);
    off ^= (r & 7) << 4;
    return *(const short8v*)((const char*)lds + off);
}

// Stage a 128x256 bf16 tile (row-major, rowstride elems) into swizzled LDS (rowbytes 512).
__device__ __forceinline__ void stage128x256(const u16* __restrict__ g, int row0, int rowmax,
                                             int rowstride, int col0, u16* lds, int tid) {
    #pragma unroll
    for (int it = 0; it < 16; ++it) {
        int chunk = tid + it * 256;
        int r = chunk >> 5;
        int kc = (chunk & 31) << 3;
        short8v v = {0, 0, 0, 0, 0, 0, 0, 0};
        if (row0 + r < rowmax)
            v = *(const short8v*)(g + (size_t)(row0 + r) * rowstride + col0 + kc);
        int off = (r * 512 + kc * 2) ^ ((r & 7) << 4);
        *(short8v*)((char*)lds + off) = v;
    }
}

// ---------------- mega setup: all independent prep in one launch ----------------
// blocks: [0,2000) wpbf | [2000,2512) wdecbf | [2512,2768) wencbf | [2768,2832) wq2+scale
//         [2832,3344) xenc | [3344,4880) decx | [4880,4888) xp0
__global__ __launch_bounds__(256) void k_setup(const int* __restrict__ S,
                                               const float* __restrict__ emb,
                                               const float* __restrict__ eWih, const float* __restrict__ eWhh,
                                               const float* __restrict__ fWih, const float* __restrict__ fWhh,
                                               const float* __restrict__ fWp,
                                               const float* __restrict__ bWih, const float* __restrict__ bWhh,
                                               const float* __restrict__ bWp,
                                               u16* __restrict__ WpBF, u16* __restrict__ WdecBF,
                                               u16* __restrict__ encW,
                                               float* __restrict__ s_enc, signed char* __restrict__ wq,
                                               u16* __restrict__ xEncBF,
                                               u16* __restrict__ decX, int* __restrict__ winTok,
                                               float* __restrict__ xp0) {
    const int b = blockIdx.x, tid = threadIdx.x;
    if (b < 2000) {                                   // Wp -> bf16
        int chunk = b * 256 + tid;
        int kc = (chunk & 31) << 3;
        int v = (chunk >> 5) % 8000;
        int d = chunk / (8000 * 32);
        const float* src = (d ? bWp : fWp) + (size_t)v * 256 + kc;
        u16 t8[8];
        #pragma unroll
        for (int j = 0; j < 8; ++j) t8[j] = f2bf(src[j]);
        *(short8v*)(WpBF + ((size_t)d * 8000 + v) * 256 + kc) = *(short8v*)t8;
    } else if (b < 2512) {                            // Wdec -> bf16 [Whh|Wih]
        int chunk = (b - 2000) * 256 + tid;
        int kc = (chunk & 63) << 3;
        int r = (chunk >> 6) & 1023;
        int d = chunk >> 16;
        const float* Whh = d ? bWhh : fWhh;
        const float* Wih = d ? bWih : fWih;
        const float* src = (kc < 256) ? (Whh + (size_t)r * 256 + kc) : (Wih + (size_t)r * 256 + (kc - 256));
        u16 t8[8];
        #pragma unroll
        for (int j = 0; j < 8; ++j) t8[j] = f2bf(src[j]);
        *(short8v*)(WdecBF + ((size_t)d * 1024 + r) * 512 + kc) = *(short8v*)t8;
    } else if (b < 2768) {                            // encW -> bf16 [Whh|Wih]
        int chunk = (b - 2512) * 256 + tid;
        int kc = (chunk & 63) << 3;
        int r = chunk >> 6;
        const float* src = (kc < 256) ? (eWhh + (size_t)r * 256 + kc) : (eWih + (size_t)r * 256 + (kc - 256));
        u16 t8[8];
        #pragma unroll
        for (int j = 0; j < 8; ++j) t8[j] = f2bf(src[j]);
        *(short8v*)(encW + (size_t)r * 512 + kc) = *(short8v*)t8;
    } else if (b < 2832) {                            // enc Whh int8 quant (scale inline)
        int lin = (b - 2768) * 256 + tid;             // 16384
        int lane = lin & 63;
        int ks = (lin >> 6) & 3;
        int c = (lin >> 8) & 3;
        int w = lin >> 10;
        int r = c * 256 + w * 16 + (lane & 15);
        float m = 0.0f;
        for (int k = 0; k < 256; k += 4) {
            float4 v4 = *(const float4*)(eWhh + (size_t)r * 256 + k);
            m = fmaxf(m, fmaxf(fmaxf(fabsf(v4.x), fabsf(v4.y)), fmaxf(fabsf(v4.z), fabsf(v4.w))));
        }
        float sqv = (m > 0.0f) ? 127.0f / m : 0.0f;
        if (ks == 0 && lane < 16) s_enc[r] = m / 16129.0f;
        int kb = ks * 64 + ((lane >> 4) << 4);
        signed char o16[16];
        #pragma unroll
        for (int j = 0; j < 16; ++j) {
            float q = rintf(eWhh[(size_t)r * 256 + kb + j] * sqv);
            q = fminf(127.0f, fmaxf(-127.0f, q));
            o16[j] = (signed char)q;
        }
        *(int4v*)(wq + (size_t)lin * 16) = *(int4v*)o16;
    } else if (b < 3344) {                            // xEnc gather -> bf16
        int chunk = (b - 2832) * 256 + tid;           // 131072
        int kc = (chunk & 31) << 3;
        int bb = (chunk >> 5) & 15;
        int t = (chunk >> 9) & 127;
        int d = chunk >> 16;
        int tok = 0;
        if (t > 0) tok = d ? S[bb * 128 + 128 - t] : S[bb * 128 + t - 1];
        const float* src = emb + (size_t)tok * 256 + kc;
        u16 t8[8];
        #pragma unroll
        for (int j = 0; j < 8; ++j) t8[j] = f2bf(src[j]);
        *(short8v*)(xEncBF + (size_t)(((d * 128 + t) * 16) + bb) * 256 + kc) = *(short8v*)t8;
    } else if (b < 4880) {                            // decX gather -> bf16 + winTok
        int chunk = (b - 3344) * 256 + tid;           // 393216
        int kc = (chunk & 31) << 3;
        int n = (chunk >> 5) & 2047;
        int r2 = chunk >> 16;
        int s = r2 % 3, d = r2 / 3;
        int bb = n >> 7, tq = n & 127;
        int pos = min(tq + s, 127);
        int tok = d ? S[bb * 128 + 127 - pos] : S[bb * 128 + pos];
        const float* src = emb + (size_t)tok * 256 + kc;
        u16 t8[8];
        #pragma unroll
        for (int j = 0; j < 8; ++j) t8[j] = f2bf(src[j]);
        *(short8v*)(decX + ((size_t)(d * 3 + s) * NN + n) * 256 + kc) = *(short8v*)t8;
        if ((chunk & 31) == 0) winTok[(d * 3 + s) * NN + n] = tok;
    } else {                                          // xp0 (f32 exact)
        int idx = (b - 4880) * 256 + tid;             // 2048
        int d = idx >> 10, r = idx & 1023;
        const float* Wih = d ? bWih : fWih;
        float acc = 0.0f;
        for (int k = 0; k < 256; ++k) acc = fmaf(emb[k], Wih[r * 256 + k], acc);
        xp0[idx] = acc;
    }
}

// ---------------- encoder x-projection GEMM -> k_encx layout ----------------
__global__ __launch_bounds__(256) void k_xproj(const u16* __restrict__ xEncBF,
                                               const u16* __restrict__ encW,
                                               const float* __restrict__ ebih,
                                               const float* __restrict__ ebhh,
                                               float* __restrict__ xpT) {
    __shared__ u16 At[128 * 256];
    __shared__ u16 Bt[128 * 256];
    const int tid = threadIdx.x, lane = tid & 63, wid = tid >> 6;
    const int wm = wid >> 1, wv = wid & 1;
    const int r0 = blockIdx.x * 128, n0 = blockIdx.y * 128, d = blockIdx.z;
    stage128x256(xEncBF + (size_t)d * 2048 * 256, n0, 1 << 30, 256, 0, At, tid);
    stage128x256(encW, r0, 1 << 30, 512, 256, Bt, tid);
    __syncthreads();
    float4v acc[4][4];
    #pragma unroll
    for (int m = 0; m < 4; ++m)
        #pragma unroll
        for (int v = 0; v < 4; ++v) acc[m][v] = (float4v){0.f, 0.f, 0.f, 0.f};
    #pragma unroll
    for (int k = 0; k < 8; ++k) {
        short8v af[4], bf[4];
        #pragma unroll
        for (int m = 0; m < 4; ++m) af[m] = ldfrag(At, wm * 64 + m * 16, k * 32, lane, 512);
        #pragma unroll
        for (int v = 0; v < 4; ++v) bf[v] = ldfrag(Bt, wv * 64 + v * 16, k * 32, lane, 512);
        #pragma unroll
        for (int m = 0; m < 4; ++m)
            #pragma unroll
            for (int v = 0; v < 4; ++v)
                acc[m][v] = __builtin_amdgcn_mfma_f32_16x16x32_bf16(af[m], bf[v], acc[m][v], 0, 0, 0);
    }
    float bs[4]; int rg[4];
    #pragma unroll
    for (int v = 0; v < 4; ++v) {
        rg[v] = r0 + wv * 64 + v * 16 + (lane & 15);
        bs[v] = ebih[rg[v]] + ebhh[rg[v]];
    }
    #pragma unroll
    for (int m = 0; m < 4; ++m)
        #pragma unroll
        for (int i = 0; i < 4; ++i) {
            int n = n0 + wm * 64 + m * 16 + ((lane >> 4) << 2) + i;
            int t_ = n >> 4, bfull = n & 15;
            #pragma unroll
            for (int v = 0; v < 4; ++v) {
                int g = rg[v] >> 8, u = rg[v] & 255;
                size_t idx4 = (((size_t)(d * 16 + bfull) * 128 + t_) * 16 + (u >> 4)) * 16 + (u & 15);
                xpT[idx4 * 4 + g] = acc[m][v][i] + bs[v];
            }
        }
}

// ---------------- encoder + overlapped decoder-X GEMM ----------------
// Blocks 0..31: int8 recurrence (1 batch/block). Blocks 32..799 (if launched): compute
// gXdec[d][sx][n][r] = decX . Wih^T + bih + bhh (bf16) on the otherwise-idle CUs.
__global__ __launch_bounds__(1024) void k_encx(const signed char* __restrict__ wq,
                                               const float* __restrict__ s_enc,
                                               const float4v* __restrict__ xpT4,
                                               u16* __restrict__ h0bf,
                                               const u16* __restrict__ decXBF,
                                               const u16* __restrict__ WdecBF,
                                               const float* __restrict__ fbih, const float* __restrict__ fbhh,
                                               const float* __restrict__ bbih, const float* __restrict__ bbhh,
                                               u16* __restrict__ gXdec) {
    __shared__ char smem[131072];
    const int tid = threadIdx.x, lane = tid & 63, w = tid >> 6;
    const int l15 = lane & 15, hi = lane >> 4;
    if (blockIdx.x < 32) {
        // ---- encoder (identical to round-16 k_enc5, LDS via smem) ----
        signed char (*hbuf)[4096] = (signed char(*)[4096])smem;
        const int blk = blockIdx.x, d = blk >> 4, b = blk & 15;
        int4v breg[4][4];
        #pragma unroll
        for (int c = 0; c < 4; ++c)
            #pragma unroll
            for (int ks = 0; ks < 4; ++ks)
                breg[c][ks] = *(const int4v*)(wq + ((size_t)(((w * 4 + c) * 4 + ks) * 64 + lane)) * 16);
        float sreg[4];
        #pragma unroll
        for (int c = 0; c < 4; ++c) sreg[c] = s_enc[c * 256 + w * 16 + l15];
        float creg = 0.0f;
        ((long*)hbuf)[tid & 1023] = 0l;
        const bool cellane = (lane < 16);
        const int u = w * 16 + l15;
        const float4v* xbase = xpT4 + ((size_t)(d * 16 + b) * 128) * 256 + w * 16 + l15;
        float4v xv_next = {0.f, 0.f, 0.f, 0.f};
        if (cellane) xv_next = xbase[0];
        __syncthreads();
        for (int t = 0; t < 128; ++t) {
            int cur = t & 1;
            float4v xv = xv_next;
            if (cellane && t < 127) xv_next = xbase[(size_t)(t + 1) * 256];
            int4v af[4];
            #pragma unroll
            for (int ks = 0; ks < 4; ++ks) {
                int off = (l15 * 256 + ks * 64 + hi * 16) ^ ((l15 & 7) << 4);
                af[ks] = *(const int4v*)(hbuf[cur] + off);
            }
            int4v acc[4];
            #pragma unroll
            for (int c = 0; c < 4; ++c) {
                acc[c] = (int4v){0, 0, 0, 0};
                #pragma unroll
                for (int ks = 0; ks < 4; ++ks)
                    acc[c] = __builtin_amdgcn_mfma_i32_16x16x64_i8(af[ks], breg[c][ks], acc[c], 0, 0, 0);
            }
            if (cellane) {
                float gi = (float)acc[0][0] * sreg[0] + xv[0];
                float gf = (float)acc[1][0] * sreg[1] + xv[1];
                float gG = (float)acc[2][0] * sreg[2] + xv[2];
                float go = (float)acc[3][0] * sreg[3] + xv[3];
                float cn = sigf(gf) * creg + sigf(gi) * tanhsafe(gG);
                float h = sigf(go) * tanhsafe(cn);
                creg = cn;
                h0bf[((size_t)d * NN + b * 128 + t) * 256 + u] = f2bf(h);
                hbuf[cur ^ 1][u] = (signed char)rintf(h * 127.0f);   // row 0: swizzle mask = 0
            }
            __syncthreads();
        }
    } else {
        // ---- decoder X-GEMM: 128n x 128r tile, K=256 (Wih half of WdecBF) ----
        u16* At = (u16*)smem;                 // 64KB swizzled
        u16* Bt = (u16*)(smem + 65536);       // 64KB swizzled
        const int bi = blockIdx.x - 32;
        const int rt = bi & 7, nt = (bi >> 3) & 15, rest = bi >> 7;  // rest 0..5
        const int sx = rest % 3, d = rest / 3;
        const int r0 = rt * 128, n0 = nt * 128;
        const int wm = w >> 2, wv = w & 3;    // 4 row-groups x 4 col-groups
        // stage A = decX[d][sx] rows n0..n0+127 (256 k), B = Wdec rows r0..r0+127 cols 256..511
        const u16* Asrc = decXBF + (size_t)(d * 3 + sx) * NN * 256;
        const u16* Bsrc = WdecBF + (size_t)d * 1024 * 512;
        #pragma unroll
        for (int it = 0; it < 4; ++it) {
            int chunk = tid + it * 1024;      // 4096
            int r = chunk >> 5, kc = (chunk & 31) << 3;
            short8v va = *(const short8v*)(Asrc + (size_t)(n0 + r) * 256 + kc);
            short8v vb = *(const short8v*)(Bsrc + (size_t)(r0 + r) * 512 + 256 + kc);
            int off = (r * 512 + kc * 2) ^ ((r & 7) << 4);
            *(short8v*)((char*)At + off) = va;
            *(short8v*)((char*)Bt + off) = vb;
        }
        __syncthreads();
        float4v acc[2][2];
        #pragma unroll
        for (int m = 0; m < 2; ++m)
            #pragma unroll
            for (int v = 0; v < 2; ++v) acc[m][v] = (float4v){0.f, 0.f, 0.f, 0.f};
        #pragma unroll
        for (int kk = 0; kk < 8; ++kk) {
            short8v af[2], bf[2];
            #pragma unroll
            for (int m = 0; m < 2; ++m) af[m] = ldfrag(At, wm * 32 + m * 16, kk * 32, lane, 512);
            #pragma unroll
            for (int v = 0; v < 2; ++v) bf[v] = ldfrag(Bt, wv * 32 + v * 16, kk * 32, lane, 512);
            #pragma unroll
            for (int m = 0; m < 2; ++m)
                #pragma unroll
                for (int v = 0; v < 2; ++v)
                    acc[m][v] = __builtin_amdgcn_mfma_f32_16x16x32_bf16(af[m], bf[v], acc[m][v], 0, 0, 0);
        }
        const float* bih = d ? bbih : fbih;
        const float* bhh = d ? bbhh : fbhh;
        #pragma unroll
        for (int m = 0; m < 2; ++m)
            #pragma unroll
            for (int i = 0; i < 4; ++i) {
                int n = n0 + wm * 32 + m * 16 + hi * 4 + i;
                #pragma unroll
                for (int v = 0; v < 2; ++v) {
                    int r = r0 + wv * 32 + v * 16 + l15;
                    float val = acc[m][v][i] + bih[r] + bhh[r];
                    gXdec[((size_t)(d * 3 + sx) * NN + n) * 1024 + r] = f2bf(val);
                }
            }
    }
}

// ---------------- decoder gate GEMM (MFMA, 128x128 tile) ----------------
// gXdec != null && s>=1: single Whh phase + epilogue add of precomputed X projection.
__global__ __launch_bounds__(256) void k_decmm(const u16* __restrict__ Ah, size_t ahStride,
                                               const u16* __restrict__ Axx, size_t axStride,
                                               const u16* __restrict__ Wdec,
                                               const float* __restrict__ bihf, const float* __restrict__ bhhf,
                                               const float* __restrict__ bihb, const float* __restrict__ bhhb,
                                               const float* __restrict__ xp0, int s,
                                               const u16* __restrict__ gXdec,
                                               float* __restrict__ gBuf) {
    __shared__ u16 At[128 * 256];
    __shared__ u16 Bt[128 * 256];
    const int tid = threadIdx.x, lane = tid & 63, wid = tid >> 6;
    const int wm = wid >> 1, wv = wid & 1;
    const int r0 = blockIdx.x * 128, n0 = blockIdx.y * 128, d = blockIdx.z;
    float4v acc[4][4];
    #pragma unroll
    for (int m = 0; m < 4; ++m)
        #pragma unroll
        for (int v = 0; v < 4; ++v) acc[m][v] = (float4v){0.f, 0.f, 0.f, 0.f};
    const int useX = (s >= 1);
    const int nph = (useX && !gXdec) ? 2 : 1;
    for (int ph = 0; ph < nph; ++ph) {
        const u16* Asrc = (ph == 0) ? (Ah + (size_t)d * ahStride) : (Axx + (size_t)d * axStride);
        stage128x256(Asrc, n0, 1 << 30, 256, 0, At, tid);
        stage128x256(Wdec + (size_t)d * 1024 * 512, r0, 1 << 30, 512, ph * 256, Bt, tid);
        __syncthreads();
        #pragma unroll
        for (int k = 0; k < 8; ++k) {
            short8v af[4], bf[4];
            #pragma unroll
            for (int m = 0; m < 4; ++m) af[m] = ldfrag(At, wm * 64 + m * 16, k * 32, lane, 512);
            #pragma unroll
            for (int v = 0; v < 4; ++v) bf[v] = ldfrag(Bt, wv * 64 + v * 16, k * 32, lane, 512);
            #pragma unroll
            for (int m = 0; m < 4; ++m)
                #pragma unroll
                for (int v = 0; v < 4; ++v)
                    acc[m][v] = __builtin_amdgcn_mfma_f32_16x16x32_bf16(af[m], bf[v], acc[m][v], 0, 0, 0);
        }
        __syncthreads();
    }
    const float* bih = d ? bihb : bihf;
    const float* bhh = d ? bhhb : bhhf;
    int rg[4];
    float bs[4] = {0.f, 0.f, 0.f, 0.f};
    #pragma unroll
    for (int v = 0; v < 4; ++v) {
        rg[v] = r0 + wv * 64 + v * 16 + (lane & 15);
        if (!useX) bs[v] = bih[rg[v]] + bhh[rg[v]] + xp0[d * 1024 + rg[v]];
        else if (!gXdec) bs[v] = bih[rg[v]] + bhh[rg[v]];
    }
    #pragma unroll
    for (int m = 0; m < 4; ++m)
        #pragma unroll
        for (int i = 0; i < 4; ++i) {
            int n = n0 + wm * 64 + m * 16 + ((lane >> 4) << 2) + i;
            #pragma unroll
            for (int v = 0; v < 4; ++v) {
                float g = acc[m][v][i] + bs[v];
                if (useX && gXdec)
                    g += bf2f(gXdec[((size_t)(d * 3 + s - 1) * NN + n) * 1024 + rg[v]]);
                gBuf[((size_t)d * NN + n) * 1024 + rg[v]] = g;
            }
        }
}

// ---------------- decoder cell ----------------
__global__ __launch_bounds__(256) void k_deccell(const float* __restrict__ gBuf,
                                                 const u16* __restrict__ h0bf,
                                                 float* __restrict__ cDec,
                                                 u16* __restrict__ hsBF, int s) {
    int flat = blockIdx.x * 256 + threadIdx.x;  // 2*2048*256
    int j = flat & 255;
    int n = (flat >> 8) & 2047;
    int d = flat >> 19;
    const float* g = gBuf + ((size_t)d * NN + n) * 1024;
    float gi = g[j], gf = g[j + 256], gg = g[j + 512], go = g[j + 768];
    float cprev = (s == 0) ? bf2f(h0bf[flat]) : cDec[flat];
    float cn = sigf(gf) * cprev + sigf(gi) * tanhsafe(gg);
    float h = sigf(go) * tanhsafe(cn);
    cDec[flat] = cn;
    hsBF[((size_t)(d * 4 + s) * NN + n) * 256 + j] = f2bf(h);
}

// ---------------- projection v8: XCD-bound chunks + A-fragments hoisted ----------------
__global__ __launch_bounds__(512, 2) void k_proj8(const u16* __restrict__ hsBF,
                                                  const u16* __restrict__ WpBF,
                                                  const float* __restrict__ bpf, const float* __restrict__ bpb,
                                                  const int* __restrict__ winTok,
                                                  float* __restrict__ partials,
                                                  float* __restrict__ gchar, float* __restrict__ gtag) {
    __shared__ u16 At[128 * 256];        // 64KB, full K, swizzled (rowbytes 512)
    __shared__ u16 Bt[2][64 * 256];      // 2x32KB double buffer, full K, swizzled
    const int tid = threadIdx.x, lane = tid & 63, w = tid >> 6;
    const int wm = w >> 1, wv = w & 1;   // 4 row-groups x 2 col-groups
    const int l15 = lane & 15, hi = lane >> 4;
    const int L = blockIdx.x;
    const int chunkI = L & 7, idx = L >> 3;
    const int n0 = (idx & 15) * 128, d = idx >> 4;
    const int vt0 = chunkI * 16;
    const int nvt = min(16, 125 - vt0);  // 125 x 64 = 8000 v-cols exact
    const float* bp = d ? bpb : bpf;

#define LOADB8(vt_) do {                                                          \
        _Pragma("unroll")                                                         \
        for (int it = 0; it < 4; ++it) {                                          \
            int g = tid + it * 512; int r = g >> 5, kc = (g & 31) << 3;           \
            bregs[it] = *(const short8v*)(WpBF + ((size_t)d * 8000 + (vt_) * 64 + r) * 256 + kc); \
        }                                                                         \
    } while (0)
#define WRITEB8(buf_) do {                                                        \
        _Pragma("unroll")                                                         \
        for (int it = 0; it < 4; ++it) {                                          \
            int g = tid + it * 512; int r = g >> 5, kc = (g & 31) << 3;           \
            int off = (r * 512 + kc * 2) ^ ((r & 7) << 4);                        \
            *(short8v*)((char*)Bt[buf_] + off) = bregs[it];                       \
        }                                                                         \
    } while (0)

    short8v bregs[4];
    for (int s = 0; s < 4; ++s) {
        const u16* hsA = hsBF + (size_t)(d * 4 + s) * NN * 256;
        #pragma unroll
        for (int it = 0; it < 8; ++it) {
            int chunk = tid + it * 512;
            int r = chunk >> 5, kc = (chunk & 31) << 3;
            short8v v8 = *(const short8v*)(hsA + (size_t)(n0 + r) * 256 + kc);
            int off = (r * 512 + kc * 2) ^ ((r & 7) << 4);
            *(short8v*)((char*)At + off) = v8;
        }
        LOADB8(vt0);
        WRITEB8(0);
        int tok[2][4];
        #pragma unroll
        for (int m = 0; m < 2; ++m)
            #pragma unroll
            for (int i = 0; i < 4; ++i) {
                int n = n0 + wm * 32 + m * 16 + hi * 4 + i;
                tok[m][i] = (s < 3) ? winTok[(d * 3 + s) * NN + n] : -1;
            }
        float expsum[2][4] = {{0.f, 0.f, 0.f, 0.f}, {0.f, 0.f, 0.f, 0.f}};
        __syncthreads();                 // At + Bt[0] visible
        short8v afr[2][8];
        #pragma unroll
        for (int m = 0; m < 2; ++m)
            #pragma unroll
            for (int kk = 0; kk < 8; ++kk) {
                afr[m][kk] = ldfrag(At, wm * 32 + m * 16, kk * 32, lane, 512);
                asm volatile("" : "+v"(afr[m][kk]));
            }
        int cur = 0;
        for (int t = 0; t < nvt; ++t) {
            int vt = vt0 + t;
            if (t + 1 < nvt) LOADB8(vt + 1);
            float bpv[2];
            #pragma unroll
            for (int v = 0; v < 2; ++v) bpv[v] = bp[vt * 64 + wv * 32 + v * 16 + l15];
            float4v acc[2][2];
            #pragma unroll
            for (int m = 0; m < 2; ++m)
                #pragma unroll
                for (int v = 0; v < 2; ++v) acc[m][v] = (float4v){0.f, 0.f, 0.f, 0.f};
            #pragma unroll
            for (int kk = 0; kk < 8; ++kk) {
                short8v bf[2];
                #pragma unroll
                for (int v = 0; v < 2; ++v) bf[v] = ldfrag(Bt[cur], wv * 32 + v * 16, kk * 32, lane, 512);
                #pragma unroll
                for (int m = 0; m < 2; ++m)
                    #pragma unroll
                    for (int v = 0; v < 2; ++v)
                        acc[m][v] = __builtin_amdgcn_mfma_f32_16x16x32_bf16(afr[m][kk], bf[v], acc[m][v], 0, 0, 0);
            }
            #pragma unroll
            for (int m = 0; m < 2; ++m)
                #pragma unroll
                for (int i = 0; i < 4; ++i) {
                    int n = n0 + wm * 32 + m * 16 + hi * 4 + i;
                    float es = 0.0f;
                    #pragma unroll
                    for (int v = 0; v < 2; ++v) {
                        int vgv = vt * 64 + wv * 32 + v * 16 + l15;
                        float lg = acc[m][v][i] + bpv[v];
                        es += __expf(lg);
                        if (vgv == tok[m][i]) gchar[(d * 3 + s) * NN + n] = lg;
                        if (s >= 1 && vgv == 0) gtag[(d * 3 + (s - 1)) * NN + n] = lg;
                    }
                    expsum[m][i] += es;
                }
            __syncthreads();
            if (t + 1 < nvt) WRITEB8(cur ^ 1);
            __syncthreads();
            cur ^= 1;
        }
        #pragma unroll
        for (int m = 0; m < 2; ++m)
            #pragma unroll
            for (int i = 0; i < 4; ++i) {
                float e = expsum[m][i];
                #pragma unroll
                for (int off = 1; off <= 8; off <<= 1) e += __shfl_xor(e, off);
                if (l15 == 0) {
                    int n = n0 + wm * 32 + m * 16 + hi * 4 + i;
                    partials[((size_t)(d * 4 + s) * NN + n) * 16 + chunkI * 2 + wv] = e;
                }
            }
    }
#undef LOADB8
#undef WRITEB8
}

// ---------------- logZ = log(sum of 16 partials) ----------------
__global__ __launch_bounds__(256) void k_lzsum(const float* __restrict__ partials,
                                               float* __restrict__ logZ) {
    int row = blockIdx.x * 256 + threadIdx.x;  // 16384
    const float* p = partials + (size_t)row * 16;
    float s = 0.0f;
    #pragma unroll
    for (int c = 0; c < 16; ++c) s += p[c];
    logZ[row] = __logf(s);
}

// ---------------- P assembly ----------------
__global__ __launch_bounds__(256) void k_passm(const float* __restrict__ gchar,
                                               const float* __restrict__ gtag,
                                               const float* __restrict__ logZ,
                                               float* __restrict__ P) {
    int flat = blockIdx.x * 256 + threadIdx.x;  // 128*3*16
    if (flat >= 128 * 3 * 16) return;
    int b = flat & 15;
    int y = (flat >> 4) % 3;
    int x = flat / 48;
    int nf = b * 128 + min(127, max(0, x - y));
    int nb = b * 128 + 127 - x;
    float pf = 0.0f, pb = 0.0f;
    for (int ss = 0; ss <= y; ++ss) {
        pf += gchar[ss * NN + nf] - logZ[ss * NN + nf];
        pb += gchar[(3 + ss) * NN + nb] - logZ[(4 + ss) * NN + nb];
    }
    pf += gtag[y * NN + nf] - logZ[(y + 1) * NN + nf];
    pb += gtag[(3 + y) * NN + nb] - logZ[(4 + y + 1) * NN + nb];
    P[flat] = 0.5f * (pf + pb);
}

// ---------------- semi-CRF scan + loss ----------------
__global__ __launch_bounds__(64) void k_scan(const float* __restrict__ P, float* __restrict__ out) {
    __shared__ float Pl[128 * 48];
    int tid = threadIdx.x;
    #pragma unroll
    for (int it = 0; it < 96; ++it) Pl[tid + it * 64] = P[tid + it * 64];
    __syncthreads();
    if (tid < 16) {
        int b = tid;
        float b0 = 0.f, b1 = 0.f, b2 = 0.f, tot = 0.f;
        for (int j = 1; j <= 128; ++j) {
            float c0 = b0 + Pl[((j - 1) * 3 + 0) * 16 + b];
            float c1 = (j >= 2) ? b1 + Pl[((j - 1) * 3 + 1) * 16 + b] : -1e30f;
            float c2 = (j >= 3) ? b2 + Pl[((j - 1) * 3 + 2) * 16 + b] : -1e30f;
            float mx = fmaxf(c0, fmaxf(c1, c2));
            float sv = __expf(c0 - mx) + __expf(c1 - mx) + __expf(c2 - mx);
            tot = mx + __logf(sv);
            b2 = b1; b1 = b0; b0 = tot;
        }
        #pragma unroll
        for (int off = 1; off <= 8; off <<= 1) tot += __shfl_xor(tot, off);
        if (b == 0) out[0] = -tot / 16.0f;
    }
}

// ---------------- launch ----------------
extern "C" void kernel_launch(void* const* d_in, const int* in_sizes, int n_in,
                              void* d_out, int out_size, void* d_ws, size_t ws_size,
                              hipStream_t stream) {
    const int* S = (const int*)d_in[0];
    const float* emb = (const float*)d_in[1];
    const float* eWih = (const float*)d_in[2];
    const float* eWhh = (const float*)d_in[3];
    const float* ebih = (const float*)d_in[4];
    const float* ebhh = (const float*)d_in[5];
    const float* fWih = (const float*)d_in[6];
    const float* fWhh = (const float*)d_in[7];
    const float* fbih = (const float*)d_in[8];
    const float* fbhh = (const float*)d_in[9];
    const float* fWp  = (const float*)d_in[10];
    const float* fbp  = (const float*)d_in[11];
    const float* bWih = (const float*)d_in[12];
    const float* bWhh = (const float*)d_in[13];
    const float* bbih = (const float*)d_in[14];
    const float* bbhh = (const float*)d_in[15];
    const float* bWp  = (const float*)d_in[16];
    const float* bbp  = (const float*)d_in[17];

    float* w = (float*)d_ws;
    u16* WpBF    = (u16*)(w + OFF_WPBF);
    u16* WdecBF  = (u16*)(w + OFF_WDEC);
    u16* xEncBF  = (u16*)(w + OFF_XENC);
    u16* h0bf    = (u16*)(w + OFF_H0BF);
    u16* decXBF  = (u16*)(w + OFF_DECX);
    float* cDec  = w + OFF_CDEC;
    u16* hsBF    = (u16*)(w + OFF_HSBF);
    float* gBuf  = w + OFF_GBUF;
    float* xpT   = gBuf;      // aliased: consumed by k_encx before decoder writes gBuf
    float* partials = gBuf;   // aliased: used only after decoder
    float* logZ  = w + OFF_LOGZ;
    float* gchar = w + OFF_GCH;
    float* gtag  = w + OFF_GTG;
    float* Pm    = w + OFF_P;
    int* winTok  = (int*)(w + OFF_WTOK);
    float* xp0   = w + OFF_XP0;
    u16* encW    = (u16*)(w + OFF_ENCW);
    float* sEnc  = w + OFF_SENC;
    signed char* wqEnc = (signed char*)(w + OFF_WQI8);
    u16* gXdec   = (u16*)(w + OFF_GXD);

    const bool useOv = (ws_size >= WS_NEED_OV);

    k_setup<<<4888, 256, 0, stream>>>(S, emb, eWih, eWhh, fWih, fWhh, fWp,
                                      bWih, bWhh, bWp,
                                      WpBF, WdecBF, encW, sEnc, wqEnc,
                                      xEncBF, decXBF, winTok, xp0);

    k_xproj<<<dim3(8, 16, 2), 256, 0, stream>>>(xEncBF, encW, ebih, ebhh, xpT);

    k_encx<<<useOv ? 800 : 32, 1024, 0, stream>>>(wqEnc, sEnc, (const float4v*)xpT, h0bf,
                                                  decXBF, WdecBF, fbih, fbhh, bbih, bbhh,
                                                  gXdec);

    const u16* gx = useOv ? gXdec : nullptr;
    for (int s = 0; s < 4; ++s) {
        const u16* Ah; size_t ahS;
        const u16* Axx; size_t axS;
        if (s == 0) {
            Ah = h0bf; ahS = (size_t)NN * 256;
            Axx = decXBF; axS = (size_t)3 * NN * 256;  // unused
        } else {
            Ah = hsBF + (size_t)(s - 1) * NN * 256; ahS = (size_t)4 * NN * 256;
            Axx = decXBF + (size_t)(s - 1) * NN * 256; axS = (size_t)3 * NN * 256;
        }
        k_decmm<<<dim3(8, 16, 2), 256, 0, stream>>>(Ah, ahS, Axx, axS, WdecBF,
                                                    fbih, fbhh, bbih, bbhh, xp0,
                                                    s, gx, gBuf);
        k_deccell<<<4096, 256, 0, stream>>>(gBuf, h0bf, cDec, hsBF, s);
    }

    k_proj8<<<256, 512, 0, stream>>>(hsBF, WpBF, fbp, bbp, winTok,
                                     partials, gchar, gtag);
    k_lzsum<<<64, 256, 0, stream>>>(partials, logZ);
    k_passm<<<24, 256, 0, stream>>>(gchar, gtag, logZ, Pm);
    k_scan<<<1, 64, 0, stream>>>(Pm, (float*)d_out);
}